// Round 5
// baseline (315.033 us; speedup 1.0000x reference)
//
#include <hip/hip_runtime.h>
#include <hip/hip_bf16.h>

#define NEG_SLOPE 0.2f
#define GGRP 128
#define TOUT 10

// ---------------------------------------------------------------------------
// init: zero degree array, set pool accumulator to -inf
// ---------------------------------------------------------------------------
__global__ void init_kernel(int* __restrict__ deg, float* __restrict__ gpool,
                            int n, int gsize) {
    int i = blockIdx.x * blockDim.x + threadIdx.x;
    if (i < n) deg[i] = 0;
    if (i < gsize) gpool[i] = -__builtin_inff();
}

// ---------------------------------------------------------------------------
// degree: count incoming edges per dst (4 edges / thread, int4 loads)
// ---------------------------------------------------------------------------
__global__ void degree_kernel(const int* __restrict__ dst, int* __restrict__ deg, int E) {
    int i = blockIdx.x * blockDim.x + threadIdx.x;
    int base = i * 4;
    if (base + 3 < E) {
        int4 d = *(const int4*)(dst + base);
        atomicAdd(&deg[d.x], 1); atomicAdd(&deg[d.y], 1);
        atomicAdd(&deg[d.z], 1); atomicAdd(&deg[d.w], 1);
    } else {
        for (int k = base; k < E; ++k) atomicAdd(&deg[dst[k]], 1);
    }
}

// ---------------------------------------------------------------------------
// hierarchical scan: A) per-block exclusive scan + block sums
// ---------------------------------------------------------------------------
__global__ __launch_bounds__(256)
void scanA_kernel(const int* __restrict__ deg, int* __restrict__ rowptr,
                  int* __restrict__ bsum, int n) {
    __shared__ int wsum[4];
    int tid = threadIdx.x, lane = tid & 63, wid = tid >> 6;
    int idx = blockIdx.x * 256 + tid;
    int v = (idx < n) ? deg[idx] : 0;
    int x = v;
    #pragma unroll
    for (int off = 1; off < 64; off <<= 1) {
        int t = __shfl_up(x, off, 64);
        if (lane >= off) x += t;
    }
    if (lane == 63) wsum[wid] = x;
    __syncthreads();
    if (tid == 0) {
        int s = 0;
        #pragma unroll
        for (int i = 0; i < 4; ++i) { int t = wsum[i]; wsum[i] = s; s += t; }
        bsum[blockIdx.x] = s;
    }
    __syncthreads();
    int excl = x - v + wsum[wid];
    if (idx < n) rowptr[idx] = excl;
}

// B) single-wave scan of block sums (nb <= 128)
__global__ void scanB_kernel(const int* __restrict__ bsum, int* __restrict__ boff,
                             int* __restrict__ rowptr, int n, int nb) {
    int lane = threadIdx.x;           // 64 threads
    int v0 = (lane < nb) ? bsum[lane] : 0;
    int v1 = (64 + lane < nb) ? bsum[64 + lane] : 0;
    int s0 = v0, s1 = v1;
    #pragma unroll
    for (int off = 1; off < 64; off <<= 1) {
        int t0 = __shfl_up(s0, off, 64);
        int t1 = __shfl_up(s1, off, 64);
        if (lane >= off) { s0 += t0; s1 += t1; }
    }
    int tot0 = __shfl(s0, 63, 64);
    s1 += tot0;
    boff[lane] = s0 - v0;
    boff[64 + lane] = s1 - v1;
    if (lane == 63) rowptr[n] = s1;   // grand total
}

// C) apply block offsets, fill cursor
__global__ void scanC_kernel(int* __restrict__ rowptr, int* __restrict__ cursor,
                             const int* __restrict__ boff, int n) {
    int idx = blockIdx.x * blockDim.x + threadIdx.x;
    if (idx < n) {
        int r = rowptr[idx] + boff[idx >> 8];
        rowptr[idx] = r;
        cursor[idx] = r;
    }
}

// ---------------------------------------------------------------------------
// scatter edges into CSR slots (by dst) — 4 edges / thread, int4 loads
// ---------------------------------------------------------------------------
__global__ void scatter_kernel(const int* __restrict__ src, const int* __restrict__ dst,
                               int* __restrict__ cursor, int* __restrict__ csr, int E) {
    int i = blockIdx.x * blockDim.x + threadIdx.x;
    int base = i * 4;
    if (base + 3 < E) {
        int4 s = *(const int4*)(src + base);
        int4 d = *(const int4*)(dst + base);
        csr[atomicAdd(&cursor[d.x], 1)] = s.x;
        csr[atomicAdd(&cursor[d.y], 1)] = s.y;
        csr[atomicAdd(&cursor[d.z], 1)] = s.z;
        csr[atomicAdd(&cursor[d.w], 1)] = s.w;
    } else {
        for (int k = base; k < E; ++k)
            csr[atomicAdd(&cursor[dst[k]], 1)] = src[k];
    }
}

// ---------------------------------------------------------------------------
// Register-blocked GEMM: OUT[r][c] = sum_k X[r][k] * W[c][k] + b[c]
// Block tile 128 rows x 128 cols, BK=32, LDS transposed [BK][BM+4],
// thread tile 8x8, chunk-level global->reg->LDS prefetch. (unchanged r4)
// ---------------------------------------------------------------------------
template <int FIN>
__global__ __launch_bounds__(256, 2)
void gemm_tile_kernel(const float* __restrict__ X,
                      const float* __restrict__ Wl, const float* __restrict__ bl,
                      const float* __restrict__ Wr, const float* __restrict__ br,
                      float* __restrict__ xl, float* __restrict__ xr,
                      int n, int nRowBlk) {
    constexpr int BK = 32, BM = 128, LDA = BM + 4;
    constexpr int NCHUNK = FIN / BK;
    __shared__ float Xs[BK][LDA];
    __shared__ float Ws[BK][LDA];
    int tid = threadIdx.x;
    int rowBlk = blockIdx.x;
    int colBlk = 0;
    if (rowBlk >= nRowBlk) { rowBlk -= nRowBlk; colBlk = 1; }
    const float* __restrict__ Wb = colBlk ? Wr : Wl;
    const float* __restrict__ bb = colBlk ? br : bl;
    float* __restrict__ ob = colBlk ? xr : xl;
    int row0 = rowBlk * BM;

    int sr  = tid >> 3;          // 0..31
    int skq = (tid & 7) * 4;     // 0,4,..,28

    float4 xpre[4], wpre[4];

    auto load_pre = [&](int c) {
        int k0 = c * BK;
        #pragma unroll
        for (int i = 0; i < 4; ++i) {
            int r = sr + i * 32;
            int gr = row0 + r;
            float4 v = {0.f, 0.f, 0.f, 0.f};
            if (gr < n) v = *(const float4*)&X[(size_t)gr * FIN + k0 + skq];
            xpre[i] = v;
            wpre[i] = *(const float4*)&Wb[(size_t)r * FIN + k0 + skq];
        }
    };
    auto store_pre = [&]() {
        #pragma unroll
        for (int i = 0; i < 4; ++i) {
            int r = sr + i * 32;
            Xs[skq + 0][r] = xpre[i].x; Xs[skq + 1][r] = xpre[i].y;
            Xs[skq + 2][r] = xpre[i].z; Xs[skq + 3][r] = xpre[i].w;
            Ws[skq + 0][r] = wpre[i].x; Ws[skq + 1][r] = wpre[i].y;
            Ws[skq + 2][r] = wpre[i].z; Ws[skq + 3][r] = wpre[i].w;
        }
    };

    load_pre(0);
    store_pre();
    __syncthreads();

    int tx = tid & 15;           // col group
    int ty = tid >> 4;           // row group
    float acc[8][8];
    #pragma unroll
    for (int i = 0; i < 8; ++i)
        #pragma unroll
        for (int j = 0; j < 8; ++j) acc[i][j] = 0.f;

    #pragma unroll
    for (int c = 0; c < NCHUNK; ++c) {
        if (c + 1 < NCHUNK) load_pre(c + 1);
        #pragma unroll 8
        for (int k = 0; k < BK; ++k) {
            float4 a0 = *(const float4*)&Xs[k][ty * 8];
            float4 a1 = *(const float4*)&Xs[k][ty * 8 + 4];
            float4 b0 = *(const float4*)&Ws[k][tx * 8];
            float4 b1 = *(const float4*)&Ws[k][tx * 8 + 4];
            float av[8] = {a0.x, a0.y, a0.z, a0.w, a1.x, a1.y, a1.z, a1.w};
            float bv[8] = {b0.x, b0.y, b0.z, b0.w, b1.x, b1.y, b1.z, b1.w};
            #pragma unroll
            for (int i = 0; i < 8; ++i)
                #pragma unroll
                for (int j = 0; j < 8; ++j)
                    acc[i][j] = fmaf(av[i], bv[j], acc[i][j]);
        }
        if (c + 1 < NCHUNK) {
            __syncthreads();
            store_pre();
            __syncthreads();
        }
    }

    float bias[8];
    #pragma unroll
    for (int j = 0; j < 8; ++j) bias[j] = bb[tx * 8 + j];
    #pragma unroll
    for (int i = 0; i < 8; ++i) {
        int gr = row0 + ty * 8 + i;
        if (gr < n) {
            float4 o0, o1;
            o0.x = acc[i][0] + bias[0]; o0.y = acc[i][1] + bias[1];
            o0.z = acc[i][2] + bias[2]; o0.w = acc[i][3] + bias[3];
            o1.x = acc[i][4] + bias[4]; o1.y = acc[i][5] + bias[5];
            o1.z = acc[i][6] + bias[6]; o1.w = acc[i][7] + bias[7];
            *(float4*)&ob[(size_t)gr * 128 + tx * 8]     = o0;
            *(float4*)&ob[(size_t)gr * 128 + tx * 8 + 4] = o1;
        }
    }
}

// ---------------------------------------------------------------------------
// Fused GATv2 conv + Linear(HD->D).
// 4 waves / block, each wave processes 4 NODES sequentially (load balance:
// per-wave work ~ Poisson(68) instead of Poisson(17) -> sigma/mu ~12%).
// Per node: 4 edges in flight (16 lanes/edge, 8 floats/lane), depth-2
// csr+row prefetch, single-pass softmax, fused HD->D linear epilogue.
// ---------------------------------------------------------------------------
__global__ __launch_bounds__(256)
void gat_fused_kernel(const float* __restrict__ xl, const float* __restrict__ xr,
                      const float* __restrict__ att, const float* __restrict__ cb,
                      const float* __restrict__ lw, const float* __restrict__ lb,
                      const int* __restrict__ rowptr, const int* __restrict__ csr,
                      float* __restrict__ out /*[n][32]*/, int n) {
    __shared__ float lws[32][132];     // lw staged, pad 132
    __shared__ float oslot[4][128];    // per-wave conv-out vector (reused per node)
    int tid = threadIdx.x;
    #pragma unroll
    for (int i = 0; i < 16; ++i) {
        int idx = tid + i * 256;       // 4096 = 32*128
        lws[idx >> 7][idx & 127] = lw[idx];
    }
    __syncthreads();

    int wid = tid >> 6, lane = tid & 63;
    int q4  = lane >> 4;               // edge slot 0..3
    int l16 = lane & 15;
    int f8  = l16 * 8;                 // features f8..f8+7 (head = l16>>2)
    int half = lane >> 5;
    int l32  = lane & 31;

    const float4 atA = *(const float4*)(att + f8);
    const float4 atB = *(const float4*)(att + f8 + 4);
    const float4 cbA = *(const float4*)(cb + f8);
    const float4 cbB = *(const float4*)(cb + f8 + 4);
    float lbv = lb[l32];

    int ndBase = blockIdx.x * 16 + wid * 4;

    for (int j = 0; j < 4; ++j) {
        int nd = ndBase + j;
        if (nd >= n) break;            // uniform within wave

        const float4 xrA  = *(const float4*)(xr + (size_t)nd * 128 + f8);
        const float4 xrB  = *(const float4*)(xr + (size_t)nd * 128 + f8 + 4);
        const float4 xlsA = *(const float4*)(xl + (size_t)nd * 128 + f8);
        const float4 xlsB = *(const float4*)(xl + (size_t)nd * 128 + f8 + 4);

        int start = rowptr[nd], end = rowptr[nd + 1];

        float den;
        float accA[4] = {0.f, 0.f, 0.f, 0.f};
        float accB[4] = {0.f, 0.f, 0.f, 0.f};

        // self-loop (counted once, on slot 0)
        {
            float e0 = xlsA.x + xrA.x; e0 = e0 > 0.f ? e0 : NEG_SLOPE * e0;
            float e1 = xlsA.y + xrA.y; e1 = e1 > 0.f ? e1 : NEG_SLOPE * e1;
            float e2 = xlsA.z + xrA.z; e2 = e2 > 0.f ? e2 : NEG_SLOPE * e2;
            float e3 = xlsA.w + xrA.w; e3 = e3 > 0.f ? e3 : NEG_SLOPE * e3;
            float e4 = xlsB.x + xrB.x; e4 = e4 > 0.f ? e4 : NEG_SLOPE * e4;
            float e5 = xlsB.y + xrB.y; e5 = e5 > 0.f ? e5 : NEG_SLOPE * e5;
            float e6 = xlsB.z + xrB.z; e6 = e6 > 0.f ? e6 : NEG_SLOPE * e6;
            float e7 = xlsB.w + xrB.w; e7 = e7 > 0.f ? e7 : NEG_SLOPE * e7;
            float q = e0 * atA.x + e1 * atA.y + e2 * atA.z + e3 * atA.w
                    + e4 * atB.x + e5 * atB.y + e6 * atB.z + e7 * atB.w;
            q += __shfl_xor(q, 1); q += __shfl_xor(q, 2);   // head = 4 lanes
            float a = __expf(q);
            if (q4 == 0) {
                den = a;
                accA[0] = a * xlsA.x; accA[1] = a * xlsA.y;
                accA[2] = a * xlsA.z; accA[3] = a * xlsA.w;
                accB[0] = a * xlsB.x; accB[1] = a * xlsB.y;
                accB[2] = a * xlsB.z; accB[3] = a * xlsB.w;
            } else {
                den = 0.f;
            }
        }

        // edges: slot q takes i = start+q, start+q+4, ...
        int i = start + q4;
        int sA = (i < end) ? csr[i] : 0;
        int sB = (i + 4 < end) ? csr[i + 4] : 0;
        float4 pre0 = {0.f, 0.f, 0.f, 0.f}, pre1 = pre0;
        if (i < end) {
            pre0 = *(const float4*)(xl + (size_t)sA * 128 + f8);
            pre1 = *(const float4*)(xl + (size_t)sA * 128 + f8 + 4);
        }
        for (; i < end; i += 4) {
            float4 x0 = pre0, x1 = pre1;
            sA = sB;
            if (i + 8 < end) sB = csr[i + 8];
            if (i + 4 < end) {
                pre0 = *(const float4*)(xl + (size_t)sA * 128 + f8);
                pre1 = *(const float4*)(xl + (size_t)sA * 128 + f8 + 4);
            }
            float e0 = x0.x + xrA.x; e0 = e0 > 0.f ? e0 : NEG_SLOPE * e0;
            float e1 = x0.y + xrA.y; e1 = e1 > 0.f ? e1 : NEG_SLOPE * e1;
            float e2 = x0.z + xrA.z; e2 = e2 > 0.f ? e2 : NEG_SLOPE * e2;
            float e3 = x0.w + xrA.w; e3 = e3 > 0.f ? e3 : NEG_SLOPE * e3;
            float e4 = x1.x + xrB.x; e4 = e4 > 0.f ? e4 : NEG_SLOPE * e4;
            float e5 = x1.y + xrB.y; e5 = e5 > 0.f ? e5 : NEG_SLOPE * e5;
            float e6 = x1.z + xrB.z; e6 = e6 > 0.f ? e6 : NEG_SLOPE * e6;
            float e7 = x1.w + xrB.w; e7 = e7 > 0.f ? e7 : NEG_SLOPE * e7;
            float q = e0 * atA.x + e1 * atA.y + e2 * atA.z + e3 * atA.w
                    + e4 * atB.x + e5 * atB.y + e6 * atB.z + e7 * atB.w;
            q += __shfl_xor(q, 1); q += __shfl_xor(q, 2);
            float a = __expf(q);
            den += a;
            accA[0] = fmaf(a, x0.x, accA[0]); accA[1] = fmaf(a, x0.y, accA[1]);
            accA[2] = fmaf(a, x0.z, accA[2]); accA[3] = fmaf(a, x0.w, accA[3]);
            accB[0] = fmaf(a, x1.x, accB[0]); accB[1] = fmaf(a, x1.y, accB[1]);
            accB[2] = fmaf(a, x1.z, accB[2]); accB[3] = fmaf(a, x1.w, accB[3]);
        }

        // combine the four slots (xor 16, 32 preserve l16 -> same head)
        #pragma unroll
        for (int t = 0; t < 4; ++t) {
            accA[t] += __shfl_xor(accA[t], 16); accA[t] += __shfl_xor(accA[t], 32);
            accB[t] += __shfl_xor(accB[t], 16); accB[t] += __shfl_xor(accB[t], 32);
        }
        den += __shfl_xor(den, 16); den += __shfl_xor(den, 32);

        float inv = 1.0f / (den * (float)(end - start + 1));
        if (q4 == 0) {
            float4 oA, oB;
            oA.x = fmaf(accA[0], inv, cbA.x); oA.y = fmaf(accA[1], inv, cbA.y);
            oA.z = fmaf(accA[2], inv, cbA.z); oA.w = fmaf(accA[3], inv, cbA.w);
            oB.x = fmaf(accB[0], inv, cbB.x); oB.y = fmaf(accB[1], inv, cbB.y);
            oB.z = fmaf(accB[2], inv, cbB.z); oB.w = fmaf(accB[3], inv, cbB.w);
            *(float4*)&oslot[wid][f8]     = oA;
            *(float4*)&oslot[wid][f8 + 4] = oB;
        }
        asm volatile("s_waitcnt lgkmcnt(0)" ::: "memory");

        // fused linear: y[c] = sum_k o[k]*lw[c][k]; c=l32, k-range by half
        float y = 0.f;
        int kbase = half * 64;
        #pragma unroll
        for (int k = 0; k < 64; k += 4) {
            float4 lv = *(const float4*)&lws[l32][kbase + k];
            float4 ov = *(const float4*)&oslot[wid][kbase + k];
            y = fmaf(lv.x, ov.x, y);
            y = fmaf(lv.y, ov.y, y);
            y = fmaf(lv.z, ov.z, y);
            y = fmaf(lv.w, ov.w, y);
        }
        y += __shfl_xor(y, 32);
        if (half == 0) out[(size_t)nd * 32 + l32] = y + lbv;
    }
}

// ---------------------------------------------------------------------------
// global max pool over sorted batch ids (run-length + atomic flush)
// ---------------------------------------------------------------------------
__device__ __forceinline__ void atomicMaxFloat(float* addr, float val) {
    if (val >= 0.f) atomicMax((int*)addr, __float_as_int(val));
    else atomicMin((unsigned int*)addr, (unsigned int)__float_as_int(val));
}

__global__ void pool_kernel(const float* __restrict__ H, const int* __restrict__ batch,
                            float* __restrict__ g, int n) {
    int tid = threadIdx.x;
    int dim = tid & 31;
    int sub = tid >> 5;                 // 0..7
    int nodeStart = blockIdx.x * 128 + sub * 16;
    float m = -__builtin_inff();
    int cur = -1;
    for (int j = 0; j < 16; ++j) {
        int nd = nodeStart + j;
        if (nd >= n) break;
        int b = batch[nd];
        if (b != cur) {
            if (cur >= 0) atomicMaxFloat(&g[cur * 32 + dim], m);
            cur = b; m = -__builtin_inff();
        }
        m = fmaxf(m, H[nd * 32 + dim]);
    }
    if (cur >= 0) atomicMaxFloat(&g[cur * 32 + dim], m);
}

// ---------------------------------------------------------------------------
// final MLP: out = relu(g@fc1.T+b1) @ fc2.T + b2   (single block)
// ---------------------------------------------------------------------------
__global__ __launch_bounds__(256)
void fc_kernel(const float* __restrict__ g,
               const float* __restrict__ fc1W, const float* __restrict__ fc1b,
               const float* __restrict__ fc2W, const float* __restrict__ fc2b,
               float* __restrict__ out) {
    __shared__ float g1[GGRP * 32];
    int tid = threadIdx.x;
    for (int idx = tid; idx < GGRP * 32; idx += 256) {
        int r = idx >> 5, c = idx & 31;
        float acc = fc1b[c];
        #pragma unroll
        for (int k = 0; k < 32; ++k) acc = fmaf(g[r * 32 + k], fc1W[c * 32 + k], acc);
        g1[idx] = acc > 0.f ? acc : 0.f;
    }
    __syncthreads();
    for (int idx = tid; idx < GGRP * TOUT; idx += 256) {
        int r = idx / TOUT, c = idx - r * TOUT;
        float acc = fc2b[c];
        #pragma unroll
        for (int k = 0; k < 32; ++k) acc = fmaf(g1[r * 32 + k], fc2W[c * 32 + k], acc);
        out[idx] = acc;
    }
}

// ---------------------------------------------------------------------------
extern "C" void kernel_launch(void* const* d_in, const int* in_sizes, int n_in,
                              void* d_out, int out_size, void* d_ws, size_t ws_size,
                              hipStream_t stream) {
    const float* x     = (const float*)d_in[0];
    const int*   ei    = (const int*)d_in[1];     // [2][E]
    const int*   batch = (const int*)d_in[2];
    const float* Wl0 = (const float*)d_in[3];
    const float* bl0 = (const float*)d_in[4];
    const float* Wr0 = (const float*)d_in[5];
    const float* br0 = (const float*)d_in[6];
    const float* at0 = (const float*)d_in[7];
    const float* cb0 = (const float*)d_in[8];
    const float* lw0 = (const float*)d_in[9];
    const float* lb0 = (const float*)d_in[10];
    const float* Wl1 = (const float*)d_in[11];
    const float* bl1 = (const float*)d_in[12];
    const float* Wr1 = (const float*)d_in[13];
    const float* br1 = (const float*)d_in[14];
    const float* at1 = (const float*)d_in[15];
    const float* cb1 = (const float*)d_in[16];
    const float* lw1 = (const float*)d_in[17];
    const float* lb1 = (const float*)d_in[18];
    const float* fc1W = (const float*)d_in[19];
    const float* fc1b = (const float*)d_in[20];
    const float* fc2W = (const float*)d_in[21];
    const float* fc2b = (const float*)d_in[22];

    const int n = in_sizes[0] / 128;      // 30000
    const int E = in_sizes[1] / 2;        // 480000
    const int* src = ei;
    const int* dst = ei + E;
    const int nblkScan = (n + 255) / 256; // 118
    const int nRowBlk = (n + 127) / 128;  // 235
    const int E4 = (E + 3) / 4;

    // workspace layout
    size_t off = 0;
    auto alloc = [&](size_t bytes) {
        void* p = (char*)d_ws + off;
        off += (bytes + 255) & ~(size_t)255;
        return p;
    };
    float* xl    = (float*)alloc((size_t)n * 128 * 4);
    float* xr    = (float*)alloc((size_t)n * 128 * 4);
    float* hbuf  = (float*)alloc((size_t)n * 32 * 4);
    int* deg     = (int*)alloc((size_t)n * 4);
    int* rowptr  = (int*)alloc((size_t)(n + 1) * 4);
    int* cursor  = (int*)alloc((size_t)n * 4);
    int* csr     = (int*)alloc((size_t)E * 4);
    int* bsum    = (int*)alloc(128 * 4);
    int* boff    = (int*)alloc(128 * 4);
    float* gpool = (float*)alloc((size_t)GGRP * 32 * 4);

    // graph structure (shared by both convs)
    init_kernel<<<(n + 255) / 256, 256, 0, stream>>>(deg, gpool, n, GGRP * 32);
    degree_kernel<<<(E4 + 255) / 256, 256, 0, stream>>>(dst, deg, E);
    scanA_kernel<<<nblkScan, 256, 0, stream>>>(deg, rowptr, bsum, n);
    scanB_kernel<<<1, 64, 0, stream>>>(bsum, boff, rowptr, n, nblkScan);
    scanC_kernel<<<nblkScan, 256, 0, stream>>>(rowptr, cursor, boff, n);
    scatter_kernel<<<(E4 + 255) / 256, 256, 0, stream>>>(src, dst, cursor, csr, E);

    // conv 0 (fused conv+linear)
    gemm_tile_kernel<128><<<2 * nRowBlk, 256, 0, stream>>>(x, Wl0, bl0, Wr0, br0,
                                                           xl, xr, n, nRowBlk);
    gat_fused_kernel<<<(n + 15) / 16, 256, 0, stream>>>(xl, xr, at0, cb0, lw0, lb0,
                                                        rowptr, csr, hbuf, n);
    // conv 1
    gemm_tile_kernel<32><<<2 * nRowBlk, 256, 0, stream>>>(hbuf, Wl1, bl1, Wr1, br1,
                                                          xl, xr, n, nRowBlk);
    gat_fused_kernel<<<(n + 15) / 16, 256, 0, stream>>>(xl, xr, at1, cb1, lw1, lb1,
                                                        rowptr, csr, hbuf, n);

    // pool + MLP
    pool_kernel<<<(n + 127) / 128, 256, 0, stream>>>(hbuf, batch, gpool, n);
    fc_kernel<<<1, 256, 0, stream>>>(gpool, fc1W, fc1b, fc2W, fc2b, (float*)d_out);
}

// Round 6
// 307.952 us; speedup vs baseline: 1.0230x; 1.0230x over previous
//
#include <hip/hip_runtime.h>
#include <hip/hip_bf16.h>

#define NEG_SLOPE 0.2f
#define GGRP 128
#define TOUT 10

// ---------------------------------------------------------------------------
// init: zero degree array, zero csr pad (for branch-free prefetch),
// set pool accumulator to -inf
// ---------------------------------------------------------------------------
__global__ void init_kernel(int* __restrict__ deg, float* __restrict__ gpool,
                            int* __restrict__ csr_pad, int n, int gsize) {
    int i = blockIdx.x * blockDim.x + threadIdx.x;
    if (i < n) deg[i] = 0;
    if (i < gsize) gpool[i] = -__builtin_inff();
    if (i < 64) csr_pad[i] = 0;
}

// ---------------------------------------------------------------------------
// degree: count incoming edges per dst (4 edges / thread, int4 loads)
// ---------------------------------------------------------------------------
__global__ void degree_kernel(const int* __restrict__ dst, int* __restrict__ deg, int E) {
    int i = blockIdx.x * blockDim.x + threadIdx.x;
    int base = i * 4;
    if (base + 3 < E) {
        int4 d = *(const int4*)(dst + base);
        atomicAdd(&deg[d.x], 1); atomicAdd(&deg[d.y], 1);
        atomicAdd(&deg[d.z], 1); atomicAdd(&deg[d.w], 1);
    } else {
        for (int k = base; k < E; ++k) atomicAdd(&deg[dst[k]], 1);
    }
}

// ---------------------------------------------------------------------------
// hierarchical scan: A) per-block exclusive scan + block sums
// ---------------------------------------------------------------------------
__global__ __launch_bounds__(256)
void scanA_kernel(const int* __restrict__ deg, int* __restrict__ rowptr,
                  int* __restrict__ bsum, int n) {
    __shared__ int wsum[4];
    int tid = threadIdx.x, lane = tid & 63, wid = tid >> 6;
    int idx = blockIdx.x * 256 + tid;
    int v = (idx < n) ? deg[idx] : 0;
    int x = v;
    #pragma unroll
    for (int off = 1; off < 64; off <<= 1) {
        int t = __shfl_up(x, off, 64);
        if (lane >= off) x += t;
    }
    if (lane == 63) wsum[wid] = x;
    __syncthreads();
    if (tid == 0) {
        int s = 0;
        #pragma unroll
        for (int i = 0; i < 4; ++i) { int t = wsum[i]; wsum[i] = s; s += t; }
        bsum[blockIdx.x] = s;
    }
    __syncthreads();
    int excl = x - v + wsum[wid];
    if (idx < n) rowptr[idx] = excl;
}

// ---------------------------------------------------------------------------
// C) apply block offsets (each block reduces bsum itself; nb <= 128),
// fill cursor; block 0 writes rowptr[n] = grand total
// ---------------------------------------------------------------------------
__global__ __launch_bounds__(256)
void scanC_kernel(int* __restrict__ rowptr, int* __restrict__ cursor,
                  const int* __restrict__ bsum, int n, int nb) {
    __shared__ int soff_sh;
    int tid = threadIdx.x;
    int bx = blockIdx.x;
    if (tid < 64) {
        int lane = tid;
        int v = 0;
        if (lane < nb && lane < bx) v = bsum[lane];
        if (lane + 64 < nb && lane + 64 < bx) v += bsum[lane + 64];
        #pragma unroll
        for (int off = 32; off >= 1; off >>= 1) v += __shfl_xor(v, off, 64);
        if (lane == 0) soff_sh = v;
        if (bx == 0) {
            int t = 0;
            if (lane < nb) t = bsum[lane];
            if (lane + 64 < nb) t += bsum[lane + 64];
            #pragma unroll
            for (int off = 32; off >= 1; off >>= 1) t += __shfl_xor(t, off, 64);
            if (lane == 0) rowptr[n] = t;
        }
    }
    __syncthreads();
    int idx = bx * 256 + tid;
    if (idx < n) {
        int r = rowptr[idx] + soff_sh;
        rowptr[idx] = r;
        cursor[idx] = r;
    }
}

// ---------------------------------------------------------------------------
// scatter edges into CSR slots (by dst) — stores PRE-SCALED byte offsets
// (src * 512) so the gather loop needs only 32-bit adds.
// ---------------------------------------------------------------------------
__global__ void scatter_kernel(const int* __restrict__ src, const int* __restrict__ dst,
                               int* __restrict__ cursor, int* __restrict__ csr, int E) {
    int i = blockIdx.x * blockDim.x + threadIdx.x;
    int base = i * 4;
    if (base + 3 < E) {
        int4 s = *(const int4*)(src + base);
        int4 d = *(const int4*)(dst + base);
        csr[atomicAdd(&cursor[d.x], 1)] = s.x << 9;
        csr[atomicAdd(&cursor[d.y], 1)] = s.y << 9;
        csr[atomicAdd(&cursor[d.z], 1)] = s.z << 9;
        csr[atomicAdd(&cursor[d.w], 1)] = s.w << 9;
    } else {
        for (int k = base; k < E; ++k)
            csr[atomicAdd(&cursor[dst[k]], 1)] = src[k] << 9;
    }
}

// ---------------------------------------------------------------------------
// Register-blocked GEMM: OUT[r][c] = sum_k X[r][k] * W[c][k] + b[c]
// Block tile 128x128, BK=32, LDS transposed [BK][BM+4], thread tile 8x8,
// chunk-level global->reg->LDS prefetch. (unchanged from r4)
// ---------------------------------------------------------------------------
template <int FIN>
__global__ __launch_bounds__(256, 2)
void gemm_tile_kernel(const float* __restrict__ X,
                      const float* __restrict__ Wl, const float* __restrict__ bl,
                      const float* __restrict__ Wr, const float* __restrict__ br,
                      float* __restrict__ xl, float* __restrict__ xr,
                      int n, int nRowBlk) {
    constexpr int BK = 32, BM = 128, LDA = BM + 4;
    constexpr int NCHUNK = FIN / BK;
    __shared__ float Xs[BK][LDA];
    __shared__ float Ws[BK][LDA];
    int tid = threadIdx.x;
    int rowBlk = blockIdx.x;
    int colBlk = 0;
    if (rowBlk >= nRowBlk) { rowBlk -= nRowBlk; colBlk = 1; }
    const float* __restrict__ Wb = colBlk ? Wr : Wl;
    const float* __restrict__ bb = colBlk ? br : bl;
    float* __restrict__ ob = colBlk ? xr : xl;
    int row0 = rowBlk * BM;

    int sr  = tid >> 3;          // 0..31
    int skq = (tid & 7) * 4;     // 0,4,..,28

    float4 xpre[4], wpre[4];

    auto load_pre = [&](int c) {
        int k0 = c * BK;
        #pragma unroll
        for (int i = 0; i < 4; ++i) {
            int r = sr + i * 32;
            int gr = row0 + r;
            float4 v = {0.f, 0.f, 0.f, 0.f};
            if (gr < n) v = *(const float4*)&X[(size_t)gr * FIN + k0 + skq];
            xpre[i] = v;
            wpre[i] = *(const float4*)&Wb[(size_t)r * FIN + k0 + skq];
        }
    };
    auto store_pre = [&]() {
        #pragma unroll
        for (int i = 0; i < 4; ++i) {
            int r = sr + i * 32;
            Xs[skq + 0][r] = xpre[i].x; Xs[skq + 1][r] = xpre[i].y;
            Xs[skq + 2][r] = xpre[i].z; Xs[skq + 3][r] = xpre[i].w;
            Ws[skq + 0][r] = wpre[i].x; Ws[skq + 1][r] = wpre[i].y;
            Ws[skq + 2][r] = wpre[i].z; Ws[skq + 3][r] = wpre[i].w;
        }
    };

    load_pre(0);
    store_pre();
    __syncthreads();

    int tx = tid & 15;           // col group
    int ty = tid >> 4;           // row group
    float acc[8][8];
    #pragma unroll
    for (int i = 0; i < 8; ++i)
        #pragma unroll
        for (int j = 0; j < 8; ++j) acc[i][j] = 0.f;

    #pragma unroll
    for (int c = 0; c < NCHUNK; ++c) {
        if (c + 1 < NCHUNK) load_pre(c + 1);
        #pragma unroll 8
        for (int k = 0; k < BK; ++k) {
            float4 a0 = *(const float4*)&Xs[k][ty * 8];
            float4 a1 = *(const float4*)&Xs[k][ty * 8 + 4];
            float4 b0 = *(const float4*)&Ws[k][tx * 8];
            float4 b1 = *(const float4*)&Ws[k][tx * 8 + 4];
            float av[8] = {a0.x, a0.y, a0.z, a0.w, a1.x, a1.y, a1.z, a1.w};
            float bv[8] = {b0.x, b0.y, b0.z, b0.w, b1.x, b1.y, b1.z, b1.w};
            #pragma unroll
            for (int i = 0; i < 8; ++i)
                #pragma unroll
                for (int j = 0; j < 8; ++j)
                    acc[i][j] = fmaf(av[i], bv[j], acc[i][j]);
        }
        if (c + 1 < NCHUNK) {
            __syncthreads();
            store_pre();
            __syncthreads();
        }
    }

    float bias[8];
    #pragma unroll
    for (int j = 0; j < 8; ++j) bias[j] = bb[tx * 8 + j];
    #pragma unroll
    for (int i = 0; i < 8; ++i) {
        int gr = row0 + ty * 8 + i;
        if (gr < n) {
            float4 o0, o1;
            o0.x = acc[i][0] + bias[0]; o0.y = acc[i][1] + bias[1];
            o0.z = acc[i][2] + bias[2]; o0.w = acc[i][3] + bias[3];
            o1.x = acc[i][4] + bias[4]; o1.y = acc[i][5] + bias[5];
            o1.z = acc[i][6] + bias[6]; o1.w = acc[i][7] + bias[7];
            *(float4*)&ob[(size_t)gr * 128 + tx * 8]     = o0;
            *(float4*)&ob[(size_t)gr * 128 + tx * 8 + 4] = o1;
        }
    }
}

// ---------------------------------------------------------------------------
// Fused GATv2 conv + Linear(HD->D).
// One wave per node (max TLP); 4 edges in flight (16 lanes/edge, 8 floats/lane).
// csr holds PRE-SCALED byte offsets; csr padded with 64 zeros -> all prefetch
// is branch-free (garbage prefetches read row 0, never consumed).
// Single-pass softmax; fused HD->D linear epilogue via LDS slot.
// ---------------------------------------------------------------------------
__global__ __launch_bounds__(256)
void gat_fused_kernel(const float* __restrict__ xl, const float* __restrict__ xr,
                      const float* __restrict__ att, const float* __restrict__ cb,
                      const float* __restrict__ lw, const float* __restrict__ lb,
                      const int* __restrict__ rowptr, const int* __restrict__ csrb,
                      float* __restrict__ out /*[n][32]*/, int n) {
    __shared__ float lws[32][132];     // lw staged, pad 132
    __shared__ float oslot[4][128];    // per-wave conv-out vector
    int tid = threadIdx.x;
    #pragma unroll
    for (int i = 0; i < 16; ++i) {
        int idx = tid + i * 256;       // 4096 = 32*128
        lws[idx >> 7][idx & 127] = lw[idx];
    }
    __syncthreads();

    int wid = tid >> 6, lane = tid & 63;
    int nd = blockIdx.x * 4 + wid;
    if (nd >= n) return;
    int q4  = lane >> 4;               // edge slot 0..3
    int l16 = lane & 15;
    int fb  = l16 * 32;                // lane's feature byte offset (8 floats)

    const char* __restrict__ xlb = (const char*)xl;
    const char* __restrict__ xrb = (const char*)xr;
    int selfoff = nd << 9;             // nd * 512 bytes

    const float4 xrA  = *(const float4*)(xrb + selfoff + fb);
    const float4 xrB  = *(const float4*)(xrb + selfoff + fb + 16);
    const float4 atA  = *(const float4*)((const char*)att + fb);
    const float4 atB  = *(const float4*)((const char*)att + fb + 16);
    const float4 xlsA = *(const float4*)(xlb + selfoff + fb);
    const float4 xlsB = *(const float4*)(xlb + selfoff + fb + 16);

    int start = rowptr[nd], end = rowptr[nd + 1];
    float cnt = (float)(end - start + 1);

    float den;
    float accA[4], accB[4];

    // self-loop (counted once, on slot 0)
    {
        float e0 = xlsA.x + xrA.x; e0 = fmaf(NEG_SLOPE, fminf(e0, 0.f), fmaxf(e0, 0.f));
        float e1 = xlsA.y + xrA.y; e1 = fmaf(NEG_SLOPE, fminf(e1, 0.f), fmaxf(e1, 0.f));
        float e2 = xlsA.z + xrA.z; e2 = fmaf(NEG_SLOPE, fminf(e2, 0.f), fmaxf(e2, 0.f));
        float e3 = xlsA.w + xrA.w; e3 = fmaf(NEG_SLOPE, fminf(e3, 0.f), fmaxf(e3, 0.f));
        float e4 = xlsB.x + xrB.x; e4 = fmaf(NEG_SLOPE, fminf(e4, 0.f), fmaxf(e4, 0.f));
        float e5 = xlsB.y + xrB.y; e5 = fmaf(NEG_SLOPE, fminf(e5, 0.f), fmaxf(e5, 0.f));
        float e6 = xlsB.z + xrB.z; e6 = fmaf(NEG_SLOPE, fminf(e6, 0.f), fmaxf(e6, 0.f));
        float e7 = xlsB.w + xrB.w; e7 = fmaf(NEG_SLOPE, fminf(e7, 0.f), fmaxf(e7, 0.f));
        float q = e0 * atA.x + e1 * atA.y + e2 * atA.z + e3 * atA.w
                + e4 * atB.x + e5 * atB.y + e6 * atB.z + e7 * atB.w;
        q += __shfl_xor(q, 1); q += __shfl_xor(q, 2);   // head = 4 lanes
        float a = __expf(q);
        if (q4 == 0) {
            den = a;
            accA[0] = a * xlsA.x; accA[1] = a * xlsA.y;
            accA[2] = a * xlsA.z; accA[3] = a * xlsA.w;
            accB[0] = a * xlsB.x; accB[1] = a * xlsB.y;
            accB[2] = a * xlsB.z; accB[3] = a * xlsB.w;
        } else {
            den = 0.f;
            accA[0] = accA[1] = accA[2] = accA[3] = 0.f;
            accB[0] = accB[1] = accB[2] = accB[3] = 0.f;
        }
    }

    // edges: slot q takes i = start+q, start+q+4, ... — all prefetch branch-free
    int i = start + q4;
    int offA = csrb[i];
    int offB = csrb[i + 4];
    float4 pre0 = *(const float4*)(xlb + offA + fb);
    float4 pre1 = *(const float4*)(xlb + offA + fb + 16);
    for (; i < end; i += 4) {
        float4 x0 = pre0, x1 = pre1;
        offA = offB;
        offB = csrb[i + 8];
        pre0 = *(const float4*)(xlb + offA + fb);
        pre1 = *(const float4*)(xlb + offA + fb + 16);
        float e0 = x0.x + xrA.x; e0 = fmaf(NEG_SLOPE, fminf(e0, 0.f), fmaxf(e0, 0.f));
        float e1 = x0.y + xrA.y; e1 = fmaf(NEG_SLOPE, fminf(e1, 0.f), fmaxf(e1, 0.f));
        float e2 = x0.z + xrA.z; e2 = fmaf(NEG_SLOPE, fminf(e2, 0.f), fmaxf(e2, 0.f));
        float e3 = x0.w + xrA.w; e3 = fmaf(NEG_SLOPE, fminf(e3, 0.f), fmaxf(e3, 0.f));
        float e4 = x1.x + xrB.x; e4 = fmaf(NEG_SLOPE, fminf(e4, 0.f), fmaxf(e4, 0.f));
        float e5 = x1.y + xrB.y; e5 = fmaf(NEG_SLOPE, fminf(e5, 0.f), fmaxf(e5, 0.f));
        float e6 = x1.z + xrB.z; e6 = fmaf(NEG_SLOPE, fminf(e6, 0.f), fmaxf(e6, 0.f));
        float e7 = x1.w + xrB.w; e7 = fmaf(NEG_SLOPE, fminf(e7, 0.f), fmaxf(e7, 0.f));
        float q = e0 * atA.x + e1 * atA.y + e2 * atA.z + e3 * atA.w
                + e4 * atB.x + e5 * atB.y + e6 * atB.z + e7 * atB.w;
        q += __shfl_xor(q, 1); q += __shfl_xor(q, 2);
        float a = __expf(q);
        den += a;
        accA[0] = fmaf(a, x0.x, accA[0]); accA[1] = fmaf(a, x0.y, accA[1]);
        accA[2] = fmaf(a, x0.z, accA[2]); accA[3] = fmaf(a, x0.w, accA[3]);
        accB[0] = fmaf(a, x1.x, accB[0]); accB[1] = fmaf(a, x1.y, accB[1]);
        accB[2] = fmaf(a, x1.z, accB[2]); accB[3] = fmaf(a, x1.w, accB[3]);
    }

    // combine the four slots (xor 16, 32 preserve l16 -> same head)
    #pragma unroll
    for (int t = 0; t < 4; ++t) {
        accA[t] += __shfl_xor(accA[t], 16); accA[t] += __shfl_xor(accA[t], 32);
        accB[t] += __shfl_xor(accB[t], 16); accB[t] += __shfl_xor(accB[t], 32);
    }
    den += __shfl_xor(den, 16); den += __shfl_xor(den, 32);

    float inv = 1.0f / (den * cnt);
    if (q4 == 0) {
        const float4 cbA = *(const float4*)((const char*)cb + fb);
        const float4 cbB = *(const float4*)((const char*)cb + fb + 16);
        float4 oA, oB;
        oA.x = fmaf(accA[0], inv, cbA.x); oA.y = fmaf(accA[1], inv, cbA.y);
        oA.z = fmaf(accA[2], inv, cbA.z); oA.w = fmaf(accA[3], inv, cbA.w);
        oB.x = fmaf(accB[0], inv, cbB.x); oB.y = fmaf(accB[1], inv, cbB.y);
        oB.z = fmaf(accB[2], inv, cbB.z); oB.w = fmaf(accB[3], inv, cbB.w);
        *(float4*)((char*)&oslot[wid][0] + fb)      = oA;
        *(float4*)((char*)&oslot[wid][0] + fb + 16) = oB;
    }
    asm volatile("s_waitcnt lgkmcnt(0)" ::: "memory");

    // fused linear: y[c] = sum_k o[k]*lw[c][k]; c=lane&31, k-range by half
    int half = lane >> 5;
    int l32 = lane & 31;
    float y = 0.f;
    int kbase = half * 64;
    #pragma unroll
    for (int k = 0; k < 64; k += 4) {
        float4 lv = *(const float4*)&lws[l32][kbase + k];
        float4 ov = *(const float4*)&oslot[wid][kbase + k];
        y = fmaf(lv.x, ov.x, y);
        y = fmaf(lv.y, ov.y, y);
        y = fmaf(lv.z, ov.z, y);
        y = fmaf(lv.w, ov.w, y);
    }
    y += __shfl_xor(y, 32);
    if (half == 0) out[(size_t)nd * 32 + l32] = y + lb[l32];
}

// ---------------------------------------------------------------------------
// global max pool over sorted batch ids (run-length + atomic flush)
// ---------------------------------------------------------------------------
__device__ __forceinline__ void atomicMaxFloat(float* addr, float val) {
    if (val >= 0.f) atomicMax((int*)addr, __float_as_int(val));
    else atomicMin((unsigned int*)addr, (unsigned int)__float_as_int(val));
}

__global__ void pool_kernel(const float* __restrict__ H, const int* __restrict__ batch,
                            float* __restrict__ g, int n) {
    int tid = threadIdx.x;
    int dim = tid & 31;
    int sub = tid >> 5;                 // 0..7
    int nodeStart = blockIdx.x * 128 + sub * 16;
    float m = -__builtin_inff();
    int cur = -1;
    for (int j = 0; j < 16; ++j) {
        int nd = nodeStart + j;
        if (nd >= n) break;
        int b = batch[nd];
        if (b != cur) {
            if (cur >= 0) atomicMaxFloat(&g[cur * 32 + dim], m);
            cur = b; m = -__builtin_inff();
        }
        m = fmaxf(m, H[nd * 32 + dim]);
    }
    if (cur >= 0) atomicMaxFloat(&g[cur * 32 + dim], m);
}

// ---------------------------------------------------------------------------
// final MLP: out = relu(g@fc1.T+b1) @ fc2.T + b2   (single block)
// ---------------------------------------------------------------------------
__global__ __launch_bounds__(256)
void fc_kernel(const float* __restrict__ g,
               const float* __restrict__ fc1W, const float* __restrict__ fc1b,
               const float* __restrict__ fc2W, const float* __restrict__ fc2b,
               float* __restrict__ out) {
    __shared__ float g1[GGRP * 32];
    int tid = threadIdx.x;
    for (int idx = tid; idx < GGRP * 32; idx += 256) {
        int r = idx >> 5, c = idx & 31;
        float acc = fc1b[c];
        #pragma unroll
        for (int k = 0; k < 32; ++k) acc = fmaf(g[r * 32 + k], fc1W[c * 32 + k], acc);
        g1[idx] = acc > 0.f ? acc : 0.f;
    }
    __syncthreads();
    for (int idx = tid; idx < GGRP * TOUT; idx += 256) {
        int r = idx / TOUT, c = idx - r * TOUT;
        float acc = fc2b[c];
        #pragma unroll
        for (int k = 0; k < 32; ++k) acc = fmaf(g1[r * 32 + k], fc2W[c * 32 + k], acc);
        out[idx] = acc;
    }
}

// ---------------------------------------------------------------------------
extern "C" void kernel_launch(void* const* d_in, const int* in_sizes, int n_in,
                              void* d_out, int out_size, void* d_ws, size_t ws_size,
                              hipStream_t stream) {
    const float* x     = (const float*)d_in[0];
    const int*   ei    = (const int*)d_in[1];     // [2][E]
    const int*   batch = (const int*)d_in[2];
    const float* Wl0 = (const float*)d_in[3];
    const float* bl0 = (const float*)d_in[4];
    const float* Wr0 = (const float*)d_in[5];
    const float* br0 = (const float*)d_in[6];
    const float* at0 = (const float*)d_in[7];
    const float* cb0 = (const float*)d_in[8];
    const float* lw0 = (const float*)d_in[9];
    const float* lb0 = (const float*)d_in[10];
    const float* Wl1 = (const float*)d_in[11];
    const float* bl1 = (const float*)d_in[12];
    const float* Wr1 = (const float*)d_in[13];
    const float* br1 = (const float*)d_in[14];
    const float* at1 = (const float*)d_in[15];
    const float* cb1 = (const float*)d_in[16];
    const float* lw1 = (const float*)d_in[17];
    const float* lb1 = (const float*)d_in[18];
    const float* fc1W = (const float*)d_in[19];
    const float* fc1b = (const float*)d_in[20];
    const float* fc2W = (const float*)d_in[21];
    const float* fc2b = (const float*)d_in[22];

    const int n = in_sizes[0] / 128;      // 30000
    const int E = in_sizes[1] / 2;        // 480000
    const int* src = ei;
    const int* dst = ei + E;
    const int nblkScan = (n + 255) / 256; // 118
    const int nRowBlk = (n + 127) / 128;  // 235
    const int E4 = (E + 3) / 4;

    // workspace layout
    size_t off = 0;
    auto alloc = [&](size_t bytes) {
        void* p = (char*)d_ws + off;
        off += (bytes + 255) & ~(size_t)255;
        return p;
    };
    float* xl    = (float*)alloc((size_t)n * 128 * 4);
    float* xr    = (float*)alloc((size_t)n * 128 * 4);
    float* hbuf  = (float*)alloc((size_t)n * 32 * 4);
    int* deg     = (int*)alloc((size_t)n * 4);
    int* rowptr  = (int*)alloc((size_t)(n + 1) * 4);
    int* cursor  = (int*)alloc((size_t)n * 4);
    int* csr     = (int*)alloc((size_t)(E + 64) * 4);   // +64 pad for prefetch
    int* bsum    = (int*)alloc(128 * 4);
    float* gpool = (float*)alloc((size_t)GGRP * 32 * 4);

    // graph structure (shared by both convs)
    init_kernel<<<(n + 255) / 256, 256, 0, stream>>>(deg, gpool, csr + E, n, GGRP * 32);
    degree_kernel<<<(E4 + 255) / 256, 256, 0, stream>>>(dst, deg, E);
    scanA_kernel<<<nblkScan, 256, 0, stream>>>(deg, rowptr, bsum, n);
    scanC_kernel<<<nblkScan, 256, 0, stream>>>(rowptr, cursor, bsum, n, nblkScan);
    scatter_kernel<<<(E4 + 255) / 256, 256, 0, stream>>>(src, dst, cursor, csr, E);

    // conv 0 (fused conv+linear)
    gemm_tile_kernel<128><<<2 * nRowBlk, 256, 0, stream>>>(x, Wl0, bl0, Wr0, br0,
                                                           xl, xr, n, nRowBlk);
    gat_fused_kernel<<<(n + 3) / 4, 256, 0, stream>>>(xl, xr, at0, cb0, lw0, lb0,
                                                      rowptr, csr, hbuf, n);
    // conv 1
    gemm_tile_kernel<32><<<2 * nRowBlk, 256, 0, stream>>>(hbuf, Wl1, bl1, Wr1, br1,
                                                          xl, xr, n, nRowBlk);
    gat_fused_kernel<<<(n + 3) / 4, 256, 0, stream>>>(xl, xr, at1, cb1, lw1, lb1,
                                                      rowptr, csr, hbuf, n);

    // pool + MLP
    pool_kernel<<<(n + 127) / 128, 256, 0, stream>>>(hbuf, batch, gpool, n);
    fc_kernel<<<1, 256, 0, stream>>>(gpool, fc1W, fc1b, fc2W, fc2b, (float*)d_out);
}

// Round 7
// 295.975 us; speedup vs baseline: 1.0644x; 1.0405x over previous
//
#include <hip/hip_runtime.h>
#include <hip/hip_bf16.h>
#include <hip/hip_fp16.h>

#define NEG_SLOPE 0.2f
#define GGRP 128
#define TOUT 10

// ---------------------------------------------------------------------------
// init: zero degree array, zero csr pad (for branch-free prefetch),
// set pool accumulator to -inf
// ---------------------------------------------------------------------------
__global__ void init_kernel(int* __restrict__ deg, float* __restrict__ gpool,
                            int* __restrict__ csr_pad, int n, int gsize) {
    int i = blockIdx.x * blockDim.x + threadIdx.x;
    if (i < n) deg[i] = 0;
    if (i < gsize) gpool[i] = -__builtin_inff();
    if (i < 64) csr_pad[i] = 0;
}

// ---------------------------------------------------------------------------
// degree: count incoming edges per dst (4 edges / thread, int4 loads)
// ---------------------------------------------------------------------------
__global__ void degree_kernel(const int* __restrict__ dst, int* __restrict__ deg, int E) {
    int i = blockIdx.x * blockDim.x + threadIdx.x;
    int base = i * 4;
    if (base + 3 < E) {
        int4 d = *(const int4*)(dst + base);
        atomicAdd(&deg[d.x], 1); atomicAdd(&deg[d.y], 1);
        atomicAdd(&deg[d.z], 1); atomicAdd(&deg[d.w], 1);
    } else {
        for (int k = base; k < E; ++k) atomicAdd(&deg[dst[k]], 1);
    }
}

// ---------------------------------------------------------------------------
// hierarchical scan: A) per-block exclusive scan + block sums
// ---------------------------------------------------------------------------
__global__ __launch_bounds__(256)
void scanA_kernel(const int* __restrict__ deg, int* __restrict__ rowptr,
                  int* __restrict__ bsum, int n) {
    __shared__ int wsum[4];
    int tid = threadIdx.x, lane = tid & 63, wid = tid >> 6;
    int idx = blockIdx.x * 256 + tid;
    int v = (idx < n) ? deg[idx] : 0;
    int x = v;
    #pragma unroll
    for (int off = 1; off < 64; off <<= 1) {
        int t = __shfl_up(x, off, 64);
        if (lane >= off) x += t;
    }
    if (lane == 63) wsum[wid] = x;
    __syncthreads();
    if (tid == 0) {
        int s = 0;
        #pragma unroll
        for (int i = 0; i < 4; ++i) { int t = wsum[i]; wsum[i] = s; s += t; }
        bsum[blockIdx.x] = s;
    }
    __syncthreads();
    int excl = x - v + wsum[wid];
    if (idx < n) rowptr[idx] = excl;
}

// ---------------------------------------------------------------------------
// C) apply block offsets (each block reduces bsum itself; nb <= 128),
// fill cursor; block 0 writes rowptr[n] = grand total
// ---------------------------------------------------------------------------
__global__ __launch_bounds__(256)
void scanC_kernel(int* __restrict__ rowptr, int* __restrict__ cursor,
                  const int* __restrict__ bsum, int n, int nb) {
    __shared__ int soff_sh;
    int tid = threadIdx.x;
    int bx = blockIdx.x;
    if (tid < 64) {
        int lane = tid;
        int v = 0;
        if (lane < nb && lane < bx) v = bsum[lane];
        if (lane + 64 < nb && lane + 64 < bx) v += bsum[lane + 64];
        #pragma unroll
        for (int off = 32; off >= 1; off >>= 1) v += __shfl_xor(v, off, 64);
        if (lane == 0) soff_sh = v;
        if (bx == 0) {
            int t = 0;
            if (lane < nb) t = bsum[lane];
            if (lane + 64 < nb) t += bsum[lane + 64];
            #pragma unroll
            for (int off = 32; off >= 1; off >>= 1) t += __shfl_xor(t, off, 64);
            if (lane == 0) rowptr[n] = t;
        }
    }
    __syncthreads();
    int idx = bx * 256 + tid;
    if (idx < n) {
        int r = rowptr[idx] + soff_sh;
        rowptr[idx] = r;
        cursor[idx] = r;
    }
}

// ---------------------------------------------------------------------------
// scatter edges into CSR slots (by dst) — stores PRE-SCALED byte offsets
// (src * 256: fp16 row stride) so the gather loop needs only 32-bit adds.
// ---------------------------------------------------------------------------
__global__ void scatter_kernel(const int* __restrict__ src, const int* __restrict__ dst,
                               int* __restrict__ cursor, int* __restrict__ csr, int E) {
    int i = blockIdx.x * blockDim.x + threadIdx.x;
    int base = i * 4;
    if (base + 3 < E) {
        int4 s = *(const int4*)(src + base);
        int4 d = *(const int4*)(dst + base);
        csr[atomicAdd(&cursor[d.x], 1)] = s.x << 8;
        csr[atomicAdd(&cursor[d.y], 1)] = s.y << 8;
        csr[atomicAdd(&cursor[d.z], 1)] = s.z << 8;
        csr[atomicAdd(&cursor[d.w], 1)] = s.w << 8;
    } else {
        for (int k = base; k < E; ++k)
            csr[atomicAdd(&cursor[dst[k]], 1)] = src[k] << 8;
    }
}

// ---------------------------------------------------------------------------
// Register-blocked GEMM: OUT[r][c] = sum_k X[r][k] * W[c][k] + b[c]
// Block tile 128x128, BK=32, LDS transposed [BK][BM+4], thread tile 8x8,
// chunk-level global->reg->LDS prefetch. colBlk 0 (Wl -> xl) additionally
// emits a packed fp16 copy (xlh) for the gather path.
// ---------------------------------------------------------------------------
template <int FIN>
__global__ __launch_bounds__(256, 2)
void gemm_tile_kernel(const float* __restrict__ X,
                      const float* __restrict__ Wl, const float* __restrict__ bl,
                      const float* __restrict__ Wr, const float* __restrict__ br,
                      float* __restrict__ xl, float* __restrict__ xr,
                      __half* __restrict__ xlh,
                      int n, int nRowBlk) {
    constexpr int BK = 32, BM = 128, LDA = BM + 4;
    constexpr int NCHUNK = FIN / BK;
    __shared__ float Xs[BK][LDA];
    __shared__ float Ws[BK][LDA];
    int tid = threadIdx.x;
    int rowBlk = blockIdx.x;
    int colBlk = 0;
    if (rowBlk >= nRowBlk) { rowBlk -= nRowBlk; colBlk = 1; }
    const float* __restrict__ Wb = colBlk ? Wr : Wl;
    const float* __restrict__ bb = colBlk ? br : bl;
    float* __restrict__ ob = colBlk ? xr : xl;
    int row0 = rowBlk * BM;

    int sr  = tid >> 3;          // 0..31
    int skq = (tid & 7) * 4;     // 0,4,..,28

    float4 xpre[4], wpre[4];

    auto load_pre = [&](int c) {
        int k0 = c * BK;
        #pragma unroll
        for (int i = 0; i < 4; ++i) {
            int r = sr + i * 32;
            int gr = row0 + r;
            float4 v = {0.f, 0.f, 0.f, 0.f};
            if (gr < n) v = *(const float4*)&X[(size_t)gr * FIN + k0 + skq];
            xpre[i] = v;
            wpre[i] = *(const float4*)&Wb[(size_t)r * FIN + k0 + skq];
        }
    };
    auto store_pre = [&]() {
        #pragma unroll
        for (int i = 0; i < 4; ++i) {
            int r = sr + i * 32;
            Xs[skq + 0][r] = xpre[i].x; Xs[skq + 1][r] = xpre[i].y;
            Xs[skq + 2][r] = xpre[i].z; Xs[skq + 3][r] = xpre[i].w;
            Ws[skq + 0][r] = wpre[i].x; Ws[skq + 1][r] = wpre[i].y;
            Ws[skq + 2][r] = wpre[i].z; Ws[skq + 3][r] = wpre[i].w;
        }
    };

    load_pre(0);
    store_pre();
    __syncthreads();

    int tx = tid & 15;           // col group
    int ty = tid >> 4;           // row group
    float acc[8][8];
    #pragma unroll
    for (int i = 0; i < 8; ++i)
        #pragma unroll
        for (int j = 0; j < 8; ++j) acc[i][j] = 0.f;

    #pragma unroll
    for (int c = 0; c < NCHUNK; ++c) {
        if (c + 1 < NCHUNK) load_pre(c + 1);
        #pragma unroll 8
        for (int k = 0; k < BK; ++k) {
            float4 a0 = *(const float4*)&Xs[k][ty * 8];
            float4 a1 = *(const float4*)&Xs[k][ty * 8 + 4];
            float4 b0 = *(const float4*)&Ws[k][tx * 8];
            float4 b1 = *(const float4*)&Ws[k][tx * 8 + 4];
            float av[8] = {a0.x, a0.y, a0.z, a0.w, a1.x, a1.y, a1.z, a1.w};
            float bv[8] = {b0.x, b0.y, b0.z, b0.w, b1.x, b1.y, b1.z, b1.w};
            #pragma unroll
            for (int i = 0; i < 8; ++i)
                #pragma unroll
                for (int j = 0; j < 8; ++j)
                    acc[i][j] = fmaf(av[i], bv[j], acc[i][j]);
        }
        if (c + 1 < NCHUNK) {
            __syncthreads();
            store_pre();
            __syncthreads();
        }
    }

    float bias[8];
    #pragma unroll
    for (int j = 0; j < 8; ++j) bias[j] = bb[tx * 8 + j];
    #pragma unroll
    for (int i = 0; i < 8; ++i) {
        int gr = row0 + ty * 8 + i;
        if (gr < n) {
            float v[8];
            #pragma unroll
            for (int j = 0; j < 8; ++j) v[j] = acc[i][j] + bias[j];
            float4 o0 = {v[0], v[1], v[2], v[3]};
            float4 o1 = {v[4], v[5], v[6], v[7]};
            *(float4*)&ob[(size_t)gr * 128 + tx * 8]     = o0;
            *(float4*)&ob[(size_t)gr * 128 + tx * 8 + 4] = o1;
            if (colBlk == 0) {
                union { __half2 h2[4]; uint4 u; } pk;
                #pragma unroll
                for (int j = 0; j < 4; ++j)
                    pk.h2[j] = __halves2half2(__float2half_rn(v[2 * j]),
                                              __float2half_rn(v[2 * j + 1]));
                *(uint4*)&xlh[(size_t)gr * 128 + tx * 8] = pk.u;
            }
        }
    }
}

// ---------------------------------------------------------------------------
// Fused GATv2 conv + Linear(HD->D).
// One wave per node; 4 edges in flight (16 lanes/edge).
// Gathers read the PACKED fp16 xl copy (256 B/row): one 16B load per lane
// per edge, depth-2 row prefetch, branch-free (csr padded with zeros).
// Self-loop + output math in fp32. Single-pass softmax; fused HD->D linear.
// ---------------------------------------------------------------------------
__global__ __launch_bounds__(256)
void gat_fused_kernel(const float* __restrict__ xl, const __half* __restrict__ xlh,
                      const float* __restrict__ xr,
                      const float* __restrict__ att, const float* __restrict__ cb,
                      const float* __restrict__ lw, const float* __restrict__ lb,
                      const int* __restrict__ rowptr, const int* __restrict__ csrb,
                      float* __restrict__ out /*[n][32]*/, int n) {
    __shared__ float lws[32][132];     // lw staged, pad 132
    __shared__ float oslot[4][128];    // per-wave conv-out vector
    int tid = threadIdx.x;
    #pragma unroll
    for (int i = 0; i < 16; ++i) {
        int idx = tid + i * 256;       // 4096 = 32*128
        lws[idx >> 7][idx & 127] = lw[idx];
    }
    __syncthreads();

    int wid = tid >> 6, lane = tid & 63;
    int nd = blockIdx.x * 4 + wid;
    if (nd >= n) return;
    int q4  = lane >> 4;               // edge slot 0..3
    int l16 = lane & 15;
    int fb  = l16 * 32;                // fp32 feature byte offset (8 floats)
    int fbh = l16 * 16;                // fp16 feature byte offset (8 halves)

    const char* __restrict__ xlb  = (const char*)xl;
    const char* __restrict__ xlhb = (const char*)xlh;
    const char* __restrict__ xrb  = (const char*)xr;
    int selfoff = nd << 9;             // nd * 512 bytes (fp32 rows)

    const float4 xrA  = *(const float4*)(xrb + selfoff + fb);
    const float4 xrB  = *(const float4*)(xrb + selfoff + fb + 16);
    const float4 atA  = *(const float4*)((const char*)att + fb);
    const float4 atB  = *(const float4*)((const char*)att + fb + 16);
    const float4 xlsA = *(const float4*)(xlb + selfoff + fb);
    const float4 xlsB = *(const float4*)(xlb + selfoff + fb + 16);

    int start = rowptr[nd], end = rowptr[nd + 1];
    float cnt = (float)(end - start + 1);

    float den;
    float accA[4], accB[4];

    // self-loop (fp32; counted once, on slot 0)
    {
        float e0 = xlsA.x + xrA.x; e0 = fmaf(NEG_SLOPE, fminf(e0, 0.f), fmaxf(e0, 0.f));
        float e1 = xlsA.y + xrA.y; e1 = fmaf(NEG_SLOPE, fminf(e1, 0.f), fmaxf(e1, 0.f));
        float e2 = xlsA.z + xrA.z; e2 = fmaf(NEG_SLOPE, fminf(e2, 0.f), fmaxf(e2, 0.f));
        float e3 = xlsA.w + xrA.w; e3 = fmaf(NEG_SLOPE, fminf(e3, 0.f), fmaxf(e3, 0.f));
        float e4 = xlsB.x + xrB.x; e4 = fmaf(NEG_SLOPE, fminf(e4, 0.f), fmaxf(e4, 0.f));
        float e5 = xlsB.y + xrB.y; e5 = fmaf(NEG_SLOPE, fminf(e5, 0.f), fmaxf(e5, 0.f));
        float e6 = xlsB.z + xrB.z; e6 = fmaf(NEG_SLOPE, fminf(e6, 0.f), fmaxf(e6, 0.f));
        float e7 = xlsB.w + xrB.w; e7 = fmaf(NEG_SLOPE, fminf(e7, 0.f), fmaxf(e7, 0.f));
        float q = e0 * atA.x + e1 * atA.y + e2 * atA.z + e3 * atA.w
                + e4 * atB.x + e5 * atB.y + e6 * atB.z + e7 * atB.w;
        q += __shfl_xor(q, 1); q += __shfl_xor(q, 2);   // head = 4 lanes
        float a = __expf(q);
        if (q4 == 0) {
            den = a;
            accA[0] = a * xlsA.x; accA[1] = a * xlsA.y;
            accA[2] = a * xlsA.z; accA[3] = a * xlsA.w;
            accB[0] = a * xlsB.x; accB[1] = a * xlsB.y;
            accB[2] = a * xlsB.z; accB[3] = a * xlsB.w;
        } else {
            den = 0.f;
            accA[0] = accA[1] = accA[2] = accA[3] = 0.f;
            accB[0] = accB[1] = accB[2] = accB[3] = 0.f;
        }
    }

    // edges: slot q takes i = start+q, start+q+4, ... (branch-free prefetch)
    int i = start + q4;
    int offC = csrb[i + 8];
    uint4 preA = *(const uint4*)(xlhb + csrb[i] + fbh);
    uint4 preB = *(const uint4*)(xlhb + csrb[i + 4] + fbh);
    for (; i < end; i += 4) {
        uint4 hx = preA;
        preA = preB;
        preB = *(const uint4*)(xlhb + offC + fbh);
        offC = csrb[i + 12];
        float2 f01 = __half22float2(*(const __half2*)&hx.x);
        float2 f23 = __half22float2(*(const __half2*)&hx.y);
        float2 f45 = __half22float2(*(const __half2*)&hx.z);
        float2 f67 = __half22float2(*(const __half2*)&hx.w);
        float e0 = f01.x + xrA.x; e0 = fmaf(NEG_SLOPE, fminf(e0, 0.f), fmaxf(e0, 0.f));
        float e1 = f01.y + xrA.y; e1 = fmaf(NEG_SLOPE, fminf(e1, 0.f), fmaxf(e1, 0.f));
        float e2 = f23.x + xrA.z; e2 = fmaf(NEG_SLOPE, fminf(e2, 0.f), fmaxf(e2, 0.f));
        float e3 = f23.y + xrA.w; e3 = fmaf(NEG_SLOPE, fminf(e3, 0.f), fmaxf(e3, 0.f));
        float e4 = f45.x + xrB.x; e4 = fmaf(NEG_SLOPE, fminf(e4, 0.f), fmaxf(e4, 0.f));
        float e5 = f45.y + xrB.y; e5 = fmaf(NEG_SLOPE, fminf(e5, 0.f), fmaxf(e5, 0.f));
        float e6 = f67.x + xrB.z; e6 = fmaf(NEG_SLOPE, fminf(e6, 0.f), fmaxf(e6, 0.f));
        float e7 = f67.y + xrB.w; e7 = fmaf(NEG_SLOPE, fminf(e7, 0.f), fmaxf(e7, 0.f));
        float q = e0 * atA.x + e1 * atA.y + e2 * atA.z + e3 * atA.w
                + e4 * atB.x + e5 * atB.y + e6 * atB.z + e7 * atB.w;
        q += __shfl_xor(q, 1); q += __shfl_xor(q, 2);
        float a = __expf(q);
        den += a;
        accA[0] = fmaf(a, f01.x, accA[0]); accA[1] = fmaf(a, f01.y, accA[1]);
        accA[2] = fmaf(a, f23.x, accA[2]); accA[3] = fmaf(a, f23.y, accA[3]);
        accB[0] = fmaf(a, f45.x, accB[0]); accB[1] = fmaf(a, f45.y, accB[1]);
        accB[2] = fmaf(a, f67.x, accB[2]); accB[3] = fmaf(a, f67.y, accB[3]);
    }

    // combine the four slots (xor 16, 32 preserve l16 -> same head)
    #pragma unroll
    for (int t = 0; t < 4; ++t) {
        accA[t] += __shfl_xor(accA[t], 16); accA[t] += __shfl_xor(accA[t], 32);
        accB[t] += __shfl_xor(accB[t], 16); accB[t] += __shfl_xor(accB[t], 32);
    }
    den += __shfl_xor(den, 16); den += __shfl_xor(den, 32);

    float inv = 1.0f / (den * cnt);
    if (q4 == 0) {
        const float4 cbA = *(const float4*)((const char*)cb + fb);
        const float4 cbB = *(const float4*)((const char*)cb + fb + 16);
        float4 oA, oB;
        oA.x = fmaf(accA[0], inv, cbA.x); oA.y = fmaf(accA[1], inv, cbA.y);
        oA.z = fmaf(accA[2], inv, cbA.z); oA.w = fmaf(accA[3], inv, cbA.w);
        oB.x = fmaf(accB[0], inv, cbB.x); oB.y = fmaf(accB[1], inv, cbB.y);
        oB.z = fmaf(accB[2], inv, cbB.z); oB.w = fmaf(accB[3], inv, cbB.w);
        *(float4*)((char*)&oslot[wid][0] + fb)      = oA;
        *(float4*)((char*)&oslot[wid][0] + fb + 16) = oB;
    }
    asm volatile("s_waitcnt lgkmcnt(0)" ::: "memory");

    // fused linear: y[c] = sum_k o[k]*lw[c][k]; c=lane&31, k-range by half
    int half = lane >> 5;
    int l32 = lane & 31;
    float y = 0.f;
    int kbase = half * 64;
    #pragma unroll
    for (int k = 0; k < 64; k += 4) {
        float4 lv = *(const float4*)&lws[l32][kbase + k];
        float4 ov = *(const float4*)&oslot[wid][kbase + k];
        y = fmaf(lv.x, ov.x, y);
        y = fmaf(lv.y, ov.y, y);
        y = fmaf(lv.z, ov.z, y);
        y = fmaf(lv.w, ov.w, y);
    }
    y += __shfl_xor(y, 32);
    if (half == 0) out[(size_t)nd * 32 + l32] = y + lb[l32];
}

// ---------------------------------------------------------------------------
// global max pool over sorted batch ids (run-length + atomic flush)
// ---------------------------------------------------------------------------
__device__ __forceinline__ void atomicMaxFloat(float* addr, float val) {
    if (val >= 0.f) atomicMax((int*)addr, __float_as_int(val));
    else atomicMin((unsigned int*)addr, (unsigned int)__float_as_int(val));
}

__global__ void pool_kernel(const float* __restrict__ H, const int* __restrict__ batch,
                            float* __restrict__ g, int n) {
    int tid = threadIdx.x;
    int dim = tid & 31;
    int sub = tid >> 5;                 // 0..7
    int nodeStart = blockIdx.x * 128 + sub * 16;
    float m = -__builtin_inff();
    int cur = -1;
    for (int j = 0; j < 16; ++j) {
        int nd = nodeStart + j;
        if (nd >= n) break;
        int b = batch[nd];
        if (b != cur) {
            if (cur >= 0) atomicMaxFloat(&g[cur * 32 + dim], m);
            cur = b; m = -__builtin_inff();
        }
        m = fmaxf(m, H[nd * 32 + dim]);
    }
    if (cur >= 0) atomicMaxFloat(&g[cur * 32 + dim], m);
}

// ---------------------------------------------------------------------------
// final MLP: out = relu(g@fc1.T+b1) @ fc2.T + b2   (single block)
// ---------------------------------------------------------------------------
__global__ __launch_bounds__(256)
void fc_kernel(const float* __restrict__ g,
               const float* __restrict__ fc1W, const float* __restrict__ fc1b,
               const float* __restrict__ fc2W, const float* __restrict__ fc2b,
               float* __restrict__ out) {
    __shared__ float g1[GGRP * 32];
    int tid = threadIdx.x;
    for (int idx = tid; idx < GGRP * 32; idx += 256) {
        int r = idx >> 5, c = idx & 31;
        float acc = fc1b[c];
        #pragma unroll
        for (int k = 0; k < 32; ++k) acc = fmaf(g[r * 32 + k], fc1W[c * 32 + k], acc);
        g1[idx] = acc > 0.f ? acc : 0.f;
    }
    __syncthreads();
    for (int idx = tid; idx < GGRP * TOUT; idx += 256) {
        int r = idx / TOUT, c = idx - r * TOUT;
        float acc = fc2b[c];
        #pragma unroll
        for (int k = 0; k < 32; ++k) acc = fmaf(g1[r * 32 + k], fc2W[c * 32 + k], acc);
        out[idx] = acc;
    }
}

// ---------------------------------------------------------------------------
extern "C" void kernel_launch(void* const* d_in, const int* in_sizes, int n_in,
                              void* d_out, int out_size, void* d_ws, size_t ws_size,
                              hipStream_t stream) {
    const float* x     = (const float*)d_in[0];
    const int*   ei    = (const int*)d_in[1];     // [2][E]
    const int*   batch = (const int*)d_in[2];
    const float* Wl0 = (const float*)d_in[3];
    const float* bl0 = (const float*)d_in[4];
    const float* Wr0 = (const float*)d_in[5];
    const float* br0 = (const float*)d_in[6];
    const float* at0 = (const float*)d_in[7];
    const float* cb0 = (const float*)d_in[8];
    const float* lw0 = (const float*)d_in[9];
    const float* lb0 = (const float*)d_in[10];
    const float* Wl1 = (const float*)d_in[11];
    const float* bl1 = (const float*)d_in[12];
    const float* Wr1 = (const float*)d_in[13];
    const float* br1 = (const float*)d_in[14];
    const float* at1 = (const float*)d_in[15];
    const float* cb1 = (const float*)d_in[16];
    const float* lw1 = (const float*)d_in[17];
    const float* lb1 = (const float*)d_in[18];
    const float* fc1W = (const float*)d_in[19];
    const float* fc1b = (const float*)d_in[20];
    const float* fc2W = (const float*)d_in[21];
    const float* fc2b = (const float*)d_in[22];

    const int n = in_sizes[0] / 128;      // 30000
    const int E = in_sizes[1] / 2;        // 480000
    const int* src = ei;
    const int* dst = ei + E;
    const int nblkScan = (n + 255) / 256; // 118
    const int nRowBlk = (n + 127) / 128;  // 235
    const int E4 = (E + 3) / 4;

    // workspace layout
    size_t off = 0;
    auto alloc = [&](size_t bytes) {
        void* p = (char*)d_ws + off;
        off += (bytes + 255) & ~(size_t)255;
        return p;
    };
    float* xl    = (float*)alloc((size_t)n * 128 * 4);
    float* xr    = (float*)alloc((size_t)n * 128 * 4);
    __half* xlh  = (__half*)alloc((size_t)n * 128 * 2);
    float* hbuf  = (float*)alloc((size_t)n * 32 * 4);
    int* deg     = (int*)alloc((size_t)n * 4);
    int* rowptr  = (int*)alloc((size_t)(n + 1) * 4);
    int* cursor  = (int*)alloc((size_t)n * 4);
    int* csr     = (int*)alloc((size_t)(E + 64) * 4);   // +64 pad for prefetch
    int* bsum    = (int*)alloc(128 * 4);
    float* gpool = (float*)alloc((size_t)GGRP * 32 * 4);

    // graph structure (shared by both convs)
    init_kernel<<<(n + 255) / 256, 256, 0, stream>>>(deg, gpool, csr + E, n, GGRP * 32);
    degree_kernel<<<(E4 + 255) / 256, 256, 0, stream>>>(dst, deg, E);
    scanA_kernel<<<nblkScan, 256, 0, stream>>>(deg, rowptr, bsum, n);
    scanC_kernel<<<nblkScan, 256, 0, stream>>>(rowptr, cursor, bsum, n, nblkScan);
    scatter_kernel<<<(E4 + 255) / 256, 256, 0, stream>>>(src, dst, cursor, csr, E);

    // conv 0 (fused conv+linear)
    gemm_tile_kernel<128><<<2 * nRowBlk, 256, 0, stream>>>(x, Wl0, bl0, Wr0, br0,
                                                           xl, xr, xlh, n, nRowBlk);
    gat_fused_kernel<<<(n + 3) / 4, 256, 0, stream>>>(xl, xlh, xr, at0, cb0, lw0, lb0,
                                                      rowptr, csr, hbuf, n);
    // conv 1
    gemm_tile_kernel<32><<<2 * nRowBlk, 256, 0, stream>>>(hbuf, Wl1, bl1, Wr1, br1,
                                                          xl, xr, xlh, n, nRowBlk);
    gat_fused_kernel<<<(n + 3) / 4, 256, 0, stream>>>(xl, xlh, xr, at1, cb1, lw1, lb1,
                                                      rowptr, csr, hbuf, n);

    // pool + MLP
    pool_kernel<<<(n + 127) / 128, 256, 0, stream>>>(hbuf, batch, gpool, n);
    fc_kernel<<<1, 256, 0, stream>>>(gpool, fc1W, fc1b, fc2W, fc2b, (float*)d_out);
}

// Round 8
// 288.228 us; speedup vs baseline: 1.0930x; 1.0269x over previous
//
#include <hip/hip_runtime.h>
#include <hip/hip_bf16.h>
#include <hip/hip_fp16.h>

#define NEG_SLOPE 0.2f
#define GGRP 128
#define TOUT 10

typedef _Float16 half8 __attribute__((ext_vector_type(8)));
typedef float floatx4 __attribute__((ext_vector_type(4)));

// ---------------------------------------------------------------------------
// init: zero degree array, zero csr pad, set pool accumulator to -inf
// ---------------------------------------------------------------------------
__global__ void init_kernel(int* __restrict__ deg, float* __restrict__ gpool,
                            int* __restrict__ csr_pad, int n, int gsize) {
    int i = blockIdx.x * blockDim.x + threadIdx.x;
    if (i < n) deg[i] = 0;
    if (i < gsize) gpool[i] = -__builtin_inff();
    if (i < 64) csr_pad[i] = 0;
}

// ---------------------------------------------------------------------------
// cvt: fp32 -> fp16 for X (big), Wl0, Wr0 (small). 8 elems / thread.
// ---------------------------------------------------------------------------
__global__ void cvt_kernel(const float* __restrict__ X, _Float16* __restrict__ Xh,
                           const float* __restrict__ Wl, _Float16* __restrict__ Wlh,
                           const float* __restrict__ Wr, _Float16* __restrict__ Wrh,
                           int nx8, int nw8) {
    int i = blockIdx.x * blockDim.x + threadIdx.x;
    const float* s; _Float16* d; int j;
    if (i < nx8) { s = X; d = Xh; j = i; }
    else if (i < nx8 + nw8) { s = Wl; d = Wlh; j = i - nx8; }
    else if (i < nx8 + 2 * nw8) { s = Wr; d = Wrh; j = i - nx8 - nw8; }
    else return;
    float4 a = *(const float4*)(s + j * 8);
    float4 b = *(const float4*)(s + j * 8 + 4);
    union { _Float16 h[8]; uint4 u; } pk;
    pk.h[0] = (_Float16)a.x; pk.h[1] = (_Float16)a.y;
    pk.h[2] = (_Float16)a.z; pk.h[3] = (_Float16)a.w;
    pk.h[4] = (_Float16)b.x; pk.h[5] = (_Float16)b.y;
    pk.h[6] = (_Float16)b.z; pk.h[7] = (_Float16)b.w;
    *(uint4*)(d + j * 8) = pk.u;
}

// ---------------------------------------------------------------------------
// degree: count incoming edges per dst (4 edges / thread, int4 loads)
// ---------------------------------------------------------------------------
__global__ void degree_kernel(const int* __restrict__ dst, int* __restrict__ deg, int E) {
    int i = blockIdx.x * blockDim.x + threadIdx.x;
    int base = i * 4;
    if (base + 3 < E) {
        int4 d = *(const int4*)(dst + base);
        atomicAdd(&deg[d.x], 1); atomicAdd(&deg[d.y], 1);
        atomicAdd(&deg[d.z], 1); atomicAdd(&deg[d.w], 1);
    } else {
        for (int k = base; k < E; ++k) atomicAdd(&deg[dst[k]], 1);
    }
}

// ---------------------------------------------------------------------------
// scan A: per-block exclusive scan + block sums
// ---------------------------------------------------------------------------
__global__ __launch_bounds__(256)
void scanA_kernel(const int* __restrict__ deg, int* __restrict__ rowptr,
                  int* __restrict__ bsum, int n) {
    __shared__ int wsum[4];
    int tid = threadIdx.x, lane = tid & 63, wid = tid >> 6;
    int idx = blockIdx.x * 256 + tid;
    int v = (idx < n) ? deg[idx] : 0;
    int x = v;
    #pragma unroll
    for (int off = 1; off < 64; off <<= 1) {
        int t = __shfl_up(x, off, 64);
        if (lane >= off) x += t;
    }
    if (lane == 63) wsum[wid] = x;
    __syncthreads();
    if (tid == 0) {
        int s = 0;
        #pragma unroll
        for (int i = 0; i < 4; ++i) { int t = wsum[i]; wsum[i] = s; s += t; }
        bsum[blockIdx.x] = s;
    }
    __syncthreads();
    int excl = x - v + wsum[wid];
    if (idx < n) rowptr[idx] = excl;
}

// ---------------------------------------------------------------------------
// scan C: apply block offsets; block 0 writes rowptr[n]
// ---------------------------------------------------------------------------
__global__ __launch_bounds__(256)
void scanC_kernel(int* __restrict__ rowptr, int* __restrict__ cursor,
                  const int* __restrict__ bsum, int n, int nb) {
    __shared__ int soff_sh;
    int tid = threadIdx.x;
    int bx = blockIdx.x;
    if (tid < 64) {
        int lane = tid;
        int v = 0;
        if (lane < nb && lane < bx) v = bsum[lane];
        if (lane + 64 < nb && lane + 64 < bx) v += bsum[lane + 64];
        #pragma unroll
        for (int off = 32; off >= 1; off >>= 1) v += __shfl_xor(v, off, 64);
        if (lane == 0) soff_sh = v;
        if (bx == 0) {
            int t = 0;
            if (lane < nb) t = bsum[lane];
            if (lane + 64 < nb) t += bsum[lane + 64];
            #pragma unroll
            for (int off = 32; off >= 1; off >>= 1) t += __shfl_xor(t, off, 64);
            if (lane == 0) rowptr[n] = t;
        }
    }
    __syncthreads();
    int idx = bx * 256 + tid;
    if (idx < n) {
        int r = rowptr[idx] + soff_sh;
        rowptr[idx] = r;
        cursor[idx] = r;
    }
}

// ---------------------------------------------------------------------------
// scatter: CSR slots hold PRE-SCALED byte offsets (src * 256, fp16 rows)
// ---------------------------------------------------------------------------
__global__ void scatter_kernel(const int* __restrict__ src, const int* __restrict__ dst,
                               int* __restrict__ cursor, int* __restrict__ csr, int E) {
    int i = blockIdx.x * blockDim.x + threadIdx.x;
    int base = i * 4;
    if (base + 3 < E) {
        int4 s = *(const int4*)(src + base);
        int4 d = *(const int4*)(dst + base);
        csr[atomicAdd(&cursor[d.x], 1)] = s.x << 8;
        csr[atomicAdd(&cursor[d.y], 1)] = s.y << 8;
        csr[atomicAdd(&cursor[d.z], 1)] = s.z << 8;
        csr[atomicAdd(&cursor[d.w], 1)] = s.w << 8;
    } else {
        for (int k = base; k < E; ++k)
            csr[atomicAdd(&cursor[dst[k]], 1)] = src[k] << 8;
    }
}

// ---------------------------------------------------------------------------
// MFMA GEMM (conv0): xlh = fp16(X@Wl.T + bl), xr = X@Wr.T + br.
// fp16 inputs, fp32 accumulate via v_mfma_f32_16x16x32_f16.
// Wave = 16 rows x 128 cols for BOTH W matrices; no LDS (W is L2-resident).
// A-frag: lane(row=l&15) reads Xh[row][kc*32+(l>>4)*8 ..+7] (16B contiguous).
// B-frag: lane(col=l&15) reads Wh[col][same k-range] (16B contiguous).
// C/D: col=lane&15, row=(lane>>4)*4+reg  [m89-verified].
// ---------------------------------------------------------------------------
__global__ __launch_bounds__(256)
void gemm_mfma_kernel(const _Float16* __restrict__ Xh,
                      const _Float16* __restrict__ Wlh, const float* __restrict__ bl,
                      const _Float16* __restrict__ Wrh, const float* __restrict__ br,
                      _Float16* __restrict__ xlh, float* __restrict__ xr, int n) {
    int tid = threadIdx.x;
    int wave = tid >> 6, lane = tid & 63;
    int r0 = blockIdx.x * 64 + wave * 16;
    if (r0 >= n) return;
    int l15 = lane & 15;
    int lkg = lane >> 4;                 // 0..3
    int arow = r0 + l15; if (arow > n - 1) arow = n - 1;

    const char* xb  = (const char*)Xh;
    const char* wlb = (const char*)Wlh;
    const char* wrb = (const char*)Wrh;

    half8 a[4];
    #pragma unroll
    for (int kc = 0; kc < 4; ++kc)
        a[kc] = *(const half8*)(xb + (size_t)arow * 256 + kc * 64 + lkg * 16);

    floatx4 accL[8], accR[8];
    #pragma unroll
    for (int t = 0; t < 8; ++t) {
        accL[t] = (floatx4){0.f, 0.f, 0.f, 0.f};
        accR[t] = (floatx4){0.f, 0.f, 0.f, 0.f};
    }

    #pragma unroll
    for (int t = 0; t < 8; ++t) {
        int wrow = t * 16 + l15;         // W row = output col
        int wk = lkg * 16;               // byte offset of k-chunk base (8 halves)
        #pragma unroll
        for (int kc = 0; kc < 4; ++kc) {
            half8 bL = *(const half8*)(wlb + (size_t)wrow * 256 + kc * 64 + wk);
            half8 bR = *(const half8*)(wrb + (size_t)wrow * 256 + kc * 64 + wk);
            accL[t] = __builtin_amdgcn_mfma_f32_16x16x32_f16(a[kc], bL, accL[t], 0, 0, 0);
            accR[t] = __builtin_amdgcn_mfma_f32_16x16x32_f16(a[kc], bR, accR[t], 0, 0, 0);
        }
    }

    // epilogue: row = r0 + lkg*4 + j, col = t*16 + l15
    #pragma unroll
    for (int j = 0; j < 4; ++j) {
        int row = r0 + lkg * 4 + j;
        if (row < n) {
            #pragma unroll
            for (int t = 0; t < 8; ++t) {
                int col = t * 16 + l15;
                float vL = accL[t][j] + bl[col];
                float vR = accR[t][j] + br[col];
                xlh[(size_t)row * 128 + col] = (_Float16)vL;
                xr[(size_t)row * 128 + col] = vR;
            }
        }
    }
}

// ---------------------------------------------------------------------------
// VALU GEMM (conv1, FIN=32): writes xlh (fp16) for colBlk0, xr (fp32) for
// colBlk1. Block tile 128x128, BK=32, thread tile 8x8. (r4 structure)
// ---------------------------------------------------------------------------
template <int FIN>
__global__ __launch_bounds__(256, 2)
void gemm_tile_kernel(const float* __restrict__ X,
                      const float* __restrict__ Wl, const float* __restrict__ bl,
                      const float* __restrict__ Wr, const float* __restrict__ br,
                      _Float16* __restrict__ xlh, float* __restrict__ xr,
                      int n, int nRowBlk) {
    constexpr int BK = 32, BM = 128, LDA = BM + 4;
    constexpr int NCHUNK = FIN / BK;
    __shared__ float Xs[BK][LDA];
    __shared__ float Ws[BK][LDA];
    int tid = threadIdx.x;
    int rowBlk = blockIdx.x;
    int colBlk = 0;
    if (rowBlk >= nRowBlk) { rowBlk -= nRowBlk; colBlk = 1; }
    const float* __restrict__ Wb = colBlk ? Wr : Wl;
    const float* __restrict__ bb = colBlk ? br : bl;
    int row0 = rowBlk * BM;

    int sr  = tid >> 3;
    int skq = (tid & 7) * 4;

    float4 xpre[4], wpre[4];

    auto load_pre = [&](int c) {
        int k0 = c * BK;
        #pragma unroll
        for (int i = 0; i < 4; ++i) {
            int r = sr + i * 32;
            int gr = row0 + r;
            float4 v = {0.f, 0.f, 0.f, 0.f};
            if (gr < n) v = *(const float4*)&X[(size_t)gr * FIN + k0 + skq];
            xpre[i] = v;
            wpre[i] = *(const float4*)&Wb[(size_t)r * FIN + k0 + skq];
        }
    };
    auto store_pre = [&]() {
        #pragma unroll
        for (int i = 0; i < 4; ++i) {
            int r = sr + i * 32;
            Xs[skq + 0][r] = xpre[i].x; Xs[skq + 1][r] = xpre[i].y;
            Xs[skq + 2][r] = xpre[i].z; Xs[skq + 3][r] = xpre[i].w;
            Ws[skq + 0][r] = wpre[i].x; Ws[skq + 1][r] = wpre[i].y;
            Ws[skq + 2][r] = wpre[i].z; Ws[skq + 3][r] = wpre[i].w;
        }
    };

    load_pre(0);
    store_pre();
    __syncthreads();

    int tx = tid & 15;
    int ty = tid >> 4;
    float acc[8][8];
    #pragma unroll
    for (int i = 0; i < 8; ++i)
        #pragma unroll
        for (int j = 0; j < 8; ++j) acc[i][j] = 0.f;

    #pragma unroll
    for (int c = 0; c < NCHUNK; ++c) {
        if (c + 1 < NCHUNK) load_pre(c + 1);
        #pragma unroll 8
        for (int k = 0; k < BK; ++k) {
            float4 a0 = *(const float4*)&Xs[k][ty * 8];
            float4 a1 = *(const float4*)&Xs[k][ty * 8 + 4];
            float4 b0 = *(const float4*)&Ws[k][tx * 8];
            float4 b1 = *(const float4*)&Ws[k][tx * 8 + 4];
            float av[8] = {a0.x, a0.y, a0.z, a0.w, a1.x, a1.y, a1.z, a1.w};
            float bv[8] = {b0.x, b0.y, b0.z, b0.w, b1.x, b1.y, b1.z, b1.w};
            #pragma unroll
            for (int i = 0; i < 8; ++i)
                #pragma unroll
                for (int j = 0; j < 8; ++j)
                    acc[i][j] = fmaf(av[i], bv[j], acc[i][j]);
        }
        if (c + 1 < NCHUNK) {
            __syncthreads();
            store_pre();
            __syncthreads();
        }
    }

    float bias[8];
    #pragma unroll
    for (int j = 0; j < 8; ++j) bias[j] = bb[tx * 8 + j];
    #pragma unroll
    for (int i = 0; i < 8; ++i) {
        int gr = row0 + ty * 8 + i;
        if (gr < n) {
            float v[8];
            #pragma unroll
            for (int j = 0; j < 8; ++j) v[j] = acc[i][j] + bias[j];
            if (colBlk == 0) {
                union { _Float16 h[8]; uint4 u; } pk;
                #pragma unroll
                for (int j = 0; j < 8; ++j) pk.h[j] = (_Float16)v[j];
                *(uint4*)&xlh[(size_t)gr * 128 + tx * 8] = pk.u;
            } else {
                float4 o0 = {v[0], v[1], v[2], v[3]};
                float4 o1 = {v[4], v[5], v[6], v[7]};
                *(float4*)&xr[(size_t)gr * 128 + tx * 8]     = o0;
                *(float4*)&xr[(size_t)gr * 128 + tx * 8 + 4] = o1;
            }
        }
    }
}

// ---------------------------------------------------------------------------
// Fused GATv2 conv + Linear(HD->D).
// One wave per node; 4 edges in flight (16 lanes/edge). All xl accesses
// (self + gathers) read the packed fp16 copy; xr self stays fp32.
// ---------------------------------------------------------------------------
__global__ __launch_bounds__(256)
void gat_fused_kernel(const _Float16* __restrict__ xlh,
                      const float* __restrict__ xr,
                      const float* __restrict__ att, const float* __restrict__ cb,
                      const float* __restrict__ lw, const float* __restrict__ lb,
                      const int* __restrict__ rowptr, const int* __restrict__ csrb,
                      float* __restrict__ out /*[n][32]*/, int n) {
    __shared__ float lws[32][132];
    __shared__ float oslot[4][128];
    int tid = threadIdx.x;
    #pragma unroll
    for (int i = 0; i < 16; ++i) {
        int idx = tid + i * 256;
        lws[idx >> 7][idx & 127] = lw[idx];
    }
    __syncthreads();

    int wid = tid >> 6, lane = tid & 63;
    int nd = blockIdx.x * 4 + wid;
    if (nd >= n) return;
    int q4  = lane >> 4;
    int l16 = lane & 15;
    int fb  = l16 * 32;                // fp32 byte offset (8 floats)
    int fbh = l16 * 16;                // fp16 byte offset (8 halves)

    const char* __restrict__ xlhb = (const char*)xlh;
    const char* __restrict__ xrb  = (const char*)xr;

    const float4 xrA = *(const float4*)(xrb + ((size_t)nd << 9) + fb);
    const float4 xrB = *(const float4*)(xrb + ((size_t)nd << 9) + fb + 16);
    const float4 atA = *(const float4*)((const char*)att + fb);
    const float4 atB = *(const float4*)((const char*)att + fb + 16);

    float4 xlsA, xlsB;
    {
        uint4 hs = *(const uint4*)(xlhb + ((size_t)nd << 8) + fbh);
        float2 s01 = __half22float2(*(const __half2*)&hs.x);
        float2 s23 = __half22float2(*(const __half2*)&hs.y);
        float2 s45 = __half22float2(*(const __half2*)&hs.z);
        float2 s67 = __half22float2(*(const __half2*)&hs.w);
        xlsA = (float4){s01.x, s01.y, s23.x, s23.y};
        xlsB = (float4){s45.x, s45.y, s67.x, s67.y};
    }

    int start = rowptr[nd], end = rowptr[nd + 1];
    float cnt = (float)(end - start + 1);

    float den;
    float accA[4], accB[4];

    // self-loop (slot 0)
    {
        float e0 = xlsA.x + xrA.x; e0 = fmaf(NEG_SLOPE, fminf(e0, 0.f), fmaxf(e0, 0.f));
        float e1 = xlsA.y + xrA.y; e1 = fmaf(NEG_SLOPE, fminf(e1, 0.f), fmaxf(e1, 0.f));
        float e2 = xlsA.z + xrA.z; e2 = fmaf(NEG_SLOPE, fminf(e2, 0.f), fmaxf(e2, 0.f));
        float e3 = xlsA.w + xrA.w; e3 = fmaf(NEG_SLOPE, fminf(e3, 0.f), fmaxf(e3, 0.f));
        float e4 = xlsB.x + xrB.x; e4 = fmaf(NEG_SLOPE, fminf(e4, 0.f), fmaxf(e4, 0.f));
        float e5 = xlsB.y + xrB.y; e5 = fmaf(NEG_SLOPE, fminf(e5, 0.f), fmaxf(e5, 0.f));
        float e6 = xlsB.z + xrB.z; e6 = fmaf(NEG_SLOPE, fminf(e6, 0.f), fmaxf(e6, 0.f));
        float e7 = xlsB.w + xrB.w; e7 = fmaf(NEG_SLOPE, fminf(e7, 0.f), fmaxf(e7, 0.f));
        float q = e0 * atA.x + e1 * atA.y + e2 * atA.z + e3 * atA.w
                + e4 * atB.x + e5 * atB.y + e6 * atB.z + e7 * atB.w;
        q += __shfl_xor(q, 1); q += __shfl_xor(q, 2);
        float a = __expf(q);
        if (q4 == 0) {
            den = a;
            accA[0] = a * xlsA.x; accA[1] = a * xlsA.y;
            accA[2] = a * xlsA.z; accA[3] = a * xlsA.w;
            accB[0] = a * xlsB.x; accB[1] = a * xlsB.y;
            accB[2] = a * xlsB.z; accB[3] = a * xlsB.w;
        } else {
            den = 0.f;
            accA[0] = accA[1] = accA[2] = accA[3] = 0.f;
            accB[0] = accB[1] = accB[2] = accB[3] = 0.f;
        }
    }

    // edges (branch-free prefetch; csr padded with zeros)
    int i = start + q4;
    int offC = csrb[i + 8];
    uint4 preA = *(const uint4*)(xlhb + csrb[i] + fbh);
    uint4 preB = *(const uint4*)(xlhb + csrb[i + 4] + fbh);
    for (; i < end; i += 4) {
        uint4 hx = preA;
        preA = preB;
        preB = *(const uint4*)(xlhb + offC + fbh);
        offC = csrb[i + 12];
        float2 f01 = __half22float2(*(const __half2*)&hx.x);
        float2 f23 = __half22float2(*(const __half2*)&hx.y);
        float2 f45 = __half22float2(*(const __half2*)&hx.z);
        float2 f67 = __half22float2(*(const __half2*)&hx.w);
        float e0 = f01.x + xrA.x; e0 = fmaf(NEG_SLOPE, fminf(e0, 0.f), fmaxf(e0, 0.f));
        float e1 = f01.y + xrA.y; e1 = fmaf(NEG_SLOPE, fminf(e1, 0.f), fmaxf(e1, 0.f));
        float e2 = f23.x + xrA.z; e2 = fmaf(NEG_SLOPE, fminf(e2, 0.f), fmaxf(e2, 0.f));
        float e3 = f23.y + xrA.w; e3 = fmaf(NEG_SLOPE, fminf(e3, 0.f), fmaxf(e3, 0.f));
        float e4 = f45.x + xrB.x; e4 = fmaf(NEG_SLOPE, fminf(e4, 0.f), fmaxf(e4, 0.f));
        float e5 = f45.y + xrB.y; e5 = fmaf(NEG_SLOPE, fminf(e5, 0.f), fmaxf(e5, 0.f));
        float e6 = f67.x + xrB.z; e6 = fmaf(NEG_SLOPE, fminf(e6, 0.f), fmaxf(e6, 0.f));
        float e7 = f67.y + xrB.w; e7 = fmaf(NEG_SLOPE, fminf(e7, 0.f), fmaxf(e7, 0.f));
        float q = e0 * atA.x + e1 * atA.y + e2 * atA.z + e3 * atA.w
                + e4 * atB.x + e5 * atB.y + e6 * atB.z + e7 * atB.w;
        q += __shfl_xor(q, 1); q += __shfl_xor(q, 2);
        float a = __expf(q);
        den += a;
        accA[0] = fmaf(a, f01.x, accA[0]); accA[1] = fmaf(a, f01.y, accA[1]);
        accA[2] = fmaf(a, f23.x, accA[2]); accA[3] = fmaf(a, f23.y, accA[3]);
        accB[0] = fmaf(a, f45.x, accB[0]); accB[1] = fmaf(a, f45.y, accB[1]);
        accB[2] = fmaf(a, f67.x, accB[2]); accB[3] = fmaf(a, f67.y, accB[3]);
    }

    #pragma unroll
    for (int t = 0; t < 4; ++t) {
        accA[t] += __shfl_xor(accA[t], 16); accA[t] += __shfl_xor(accA[t], 32);
        accB[t] += __shfl_xor(accB[t], 16); accB[t] += __shfl_xor(accB[t], 32);
    }
    den += __shfl_xor(den, 16); den += __shfl_xor(den, 32);

    float inv = 1.0f / (den * cnt);
    if (q4 == 0) {
        const float4 cbA = *(const float4*)((const char*)cb + fb);
        const float4 cbB = *(const float4*)((const char*)cb + fb + 16);
        float4 oA, oB;
        oA.x = fmaf(accA[0], inv, cbA.x); oA.y = fmaf(accA[1], inv, cbA.y);
        oA.z = fmaf(accA[2], inv, cbA.z); oA.w = fmaf(accA[3], inv, cbA.w);
        oB.x = fmaf(accB[0], inv, cbB.x); oB.y = fmaf(accB[1], inv, cbB.y);
        oB.z = fmaf(accB[2], inv, cbB.z); oB.w = fmaf(accB[3], inv, cbB.w);
        *(float4*)((char*)&oslot[wid][0] + fb)      = oA;
        *(float4*)((char*)&oslot[wid][0] + fb + 16) = oB;
    }
    asm volatile("s_waitcnt lgkmcnt(0)" ::: "memory");

    int half = lane >> 5;
    int l32 = lane & 31;
    float y = 0.f;
    int kbase = half * 64;
    #pragma unroll
    for (int k = 0; k < 64; k += 4) {
        float4 lv = *(const float4*)&lws[l32][kbase + k];
        float4 ov = *(const float4*)&oslot[wid][kbase + k];
        y = fmaf(lv.x, ov.x, y);
        y = fmaf(lv.y, ov.y, y);
        y = fmaf(lv.z, ov.z, y);
        y = fmaf(lv.w, ov.w, y);
    }
    y += __shfl_xor(y, 32);
    if (half == 0) out[(size_t)nd * 32 + l32] = y + lb[l32];
}

// ---------------------------------------------------------------------------
// global max pool over sorted batch ids
// ---------------------------------------------------------------------------
__device__ __forceinline__ void atomicMaxFloat(float* addr, float val) {
    if (val >= 0.f) atomicMax((int*)addr, __float_as_int(val));
    else atomicMin((unsigned int*)addr, (unsigned int)__float_as_int(val));
}

__global__ void pool_kernel(const float* __restrict__ H, const int* __restrict__ batch,
                            float* __restrict__ g, int n) {
    int tid = threadIdx.x;
    int dim = tid & 31;
    int sub = tid >> 5;
    int nodeStart = blockIdx.x * 128 + sub * 16;
    float m = -__builtin_inff();
    int cur = -1;
    for (int j = 0; j < 16; ++j) {
        int nd = nodeStart + j;
        if (nd >= n) break;
        int b = batch[nd];
        if (b != cur) {
            if (cur >= 0) atomicMaxFloat(&g[cur * 32 + dim], m);
            cur = b; m = -__builtin_inff();
        }
        m = fmaxf(m, H[nd * 32 + dim]);
    }
    if (cur >= 0) atomicMaxFloat(&g[cur * 32 + dim], m);
}

// ---------------------------------------------------------------------------
// final MLP
// ---------------------------------------------------------------------------
__global__ __launch_bounds__(256)
void fc_kernel(const float* __restrict__ g,
               const float* __restrict__ fc1W, const float* __restrict__ fc1b,
               const float* __restrict__ fc2W, const float* __restrict__ fc2b,
               float* __restrict__ out) {
    __shared__ float g1[GGRP * 32];
    int tid = threadIdx.x;
    for (int idx = tid; idx < GGRP * 32; idx += 256) {
        int r = idx >> 5, c = idx & 31;
        float acc = fc1b[c];
        #pragma unroll
        for (int k = 0; k < 32; ++k) acc = fmaf(g[r * 32 + k], fc1W[c * 32 + k], acc);
        g1[idx] = acc > 0.f ? acc : 0.f;
    }
    __syncthreads();
    for (int idx = tid; idx < GGRP * TOUT; idx += 256) {
        int r = idx / TOUT, c = idx - r * TOUT;
        float acc = fc2b[c];
        #pragma unroll
        for (int k = 0; k < 32; ++k) acc = fmaf(g1[r * 32 + k], fc2W[c * 32 + k], acc);
        out[idx] = acc;
    }
}

// ---------------------------------------------------------------------------
extern "C" void kernel_launch(void* const* d_in, const int* in_sizes, int n_in,
                              void* d_out, int out_size, void* d_ws, size_t ws_size,
                              hipStream_t stream) {
    const float* x     = (const float*)d_in[0];
    const int*   ei    = (const int*)d_in[1];
    const int*   batch = (const int*)d_in[2];
    const float* Wl0 = (const float*)d_in[3];
    const float* bl0 = (const float*)d_in[4];
    const float* Wr0 = (const float*)d_in[5];
    const float* br0 = (const float*)d_in[6];
    const float* at0 = (const float*)d_in[7];
    const float* cb0 = (const float*)d_in[8];
    const float* lw0 = (const float*)d_in[9];
    const float* lb0 = (const float*)d_in[10];
    const float* Wl1 = (const float*)d_in[11];
    const float* bl1 = (const float*)d_in[12];
    const float* Wr1 = (const float*)d_in[13];
    const float* br1 = (const float*)d_in[14];
    const float* at1 = (const float*)d_in[15];
    const float* cb1 = (const float*)d_in[16];
    const float* lw1 = (const float*)d_in[17];
    const float* lb1 = (const float*)d_in[18];
    const float* fc1W = (const float*)d_in[19];
    const float* fc1b = (const float*)d_in[20];
    const float* fc2W = (const float*)d_in[21];
    const float* fc2b = (const float*)d_in[22];

    const int n = in_sizes[0] / 128;      // 30000
    const int E = in_sizes[1] / 2;        // 480000
    const int* src = ei;
    const int* dst = ei + E;
    const int nblkScan = (n + 255) / 256; // 118
    const int nRowBlk = (n + 127) / 128;  // 235
    const int E4 = (E + 3) / 4;
    const int nx8 = n * 16;               // X fp16-groups of 8
    const int nw8 = 128 * 128 / 8;        // 2048 per W

    size_t off = 0;
    auto alloc = [&](size_t bytes) {
        void* p = (char*)d_ws + off;
        off += (bytes + 255) & ~(size_t)255;
        return p;
    };
    _Float16* xh  = (_Float16*)alloc((size_t)n * 128 * 2);
    _Float16* wlh = (_Float16*)alloc(128 * 128 * 2);
    _Float16* wrh = (_Float16*)alloc(128 * 128 * 2);
    _Float16* xlh = (_Float16*)alloc((size_t)n * 128 * 2);
    float* xr    = (float*)alloc((size_t)n * 128 * 4);
    float* hbuf  = (float*)alloc((size_t)n * 32 * 4);
    int* deg     = (int*)alloc((size_t)n * 4);
    int* rowptr  = (int*)alloc((size_t)(n + 1) * 4);
    int* cursor  = (int*)alloc((size_t)n * 4);
    int* csr     = (int*)alloc((size_t)(E + 64) * 4);
    int* bsum    = (int*)alloc(128 * 4);
    float* gpool = (float*)alloc((size_t)GGRP * 32 * 4);

    // graph structure + fp16 casts
    init_kernel<<<(n + 255) / 256, 256, 0, stream>>>(deg, gpool, csr + E, n, GGRP * 32);
    cvt_kernel<<<(nx8 + 2 * nw8 + 255) / 256, 256, 0, stream>>>(x, xh, Wl0, wlh,
                                                                Wr0, wrh, nx8, nw8);
    degree_kernel<<<(E4 + 255) / 256, 256, 0, stream>>>(dst, deg, E);
    scanA_kernel<<<nblkScan, 256, 0, stream>>>(deg, rowptr, bsum, n);
    scanC_kernel<<<nblkScan, 256, 0, stream>>>(rowptr, cursor, bsum, n, nblkScan);
    scatter_kernel<<<(E4 + 255) / 256, 256, 0, stream>>>(src, dst, cursor, csr, E);

    // conv 0: MFMA gemm + fused gat/linear
    gemm_mfma_kernel<<<(n + 63) / 64, 256, 0, stream>>>(xh, wlh, bl0, wrh, br0,
                                                        xlh, xr, n);
    gat_fused_kernel<<<(n + 3) / 4, 256, 0, stream>>>(xlh, xr, at0, cb0, lw0, lb0,
                                                      rowptr, csr, hbuf, n);
    // conv 1: VALU gemm (K=32) + fused gat/linear
    gemm_tile_kernel<32><<<2 * nRowBlk, 256, 0, stream>>>(hbuf, Wl1, bl1, Wr1, br1,
                                                          xlh, xr, n, nRowBlk);
    gat_fused_kernel<<<(n + 3) / 4, 256, 0, stream>>>(xlh, xr, at1, cb1, lw1, lb1,
                                                      rowptr, csr, hbuf, n);

    // pool + MLP
    pool_kernel<<<(n + 127) / 128, 256, 0, stream>>>(hbuf, batch, gpool, n);
    fc_kernel<<<1, 256, 0, stream>>>(gpool, fc1W, fc1b, fc2W, fc2b, (float*)d_out);
}